// Round 12
// baseline (563.648 us; speedup 1.0000x reference)
//
#include <hip/hip_runtime.h>
#include <hip/hip_bf16.h>
#include <cstdint>

// Problem constants
#define Bk 32
#define Sk 256
#define Wk 32
#define Tk 16
#define Ek 300
#define Hk 128
#define Dk 128
#define NROWS (Bk*Sk)          // 8192
#define GI_N  (3*Hk*2)         // 768
#define KPAD  320              // 300 padded to multiple of 32

typedef __attribute__((ext_vector_type(8))) short short8v;
typedef __attribute__((ext_vector_type(4))) float f32x4;

// ---------------- helpers ----------------
__device__ __forceinline__ float fast_sigmoid(float x) {
    return 1.f / (1.f + __expf(-x));
}
__device__ __forceinline__ float fast_tanh(float x) {
    float ax = fabsf(x);
    float e = __expf(2.f * ax);
    float t = 1.f - 2.f / (1.f + e);
    return copysignf(t, x);
}
__device__ __forceinline__ void barrier_lgkm() {
    asm volatile("s_waitcnt lgkmcnt(0)" ::: "memory");
    __builtin_amdgcn_s_barrier();
}
// fp32 -> bf16 (RNE), finite inputs
__device__ __forceinline__ unsigned short f2bf(float f) {
    uint32_t u = __float_as_uint(f);
    uint32_t r = (u + 0x7FFFu + ((u >> 16) & 1u)) >> 16;
    return (unsigned short)r;
}
__device__ __forceinline__ float bf2f(unsigned short h) {
    return __uint_as_float(((uint32_t)h) << 16);
}

// ---------------- pack kernel ----------------
__global__ __launch_bounds__(256) void pack_kernel(
    const float* __restrict__ Wf, const float* __restrict__ Wb,
    const float* __restrict__ Whh_f, const float* __restrict__ Whh_b,
    const float* __restrict__ bf, const float* __restrict__ bb,
    const float* __restrict__ Watt, const float* __restrict__ W1,
    unsigned short* __restrict__ Bgt_hi, unsigned short* __restrict__ Bgt_lo,
    float* __restrict__ bias_gi, unsigned short* __restrict__ Wswt,
    unsigned short* __restrict__ W1H, unsigned short* __restrict__ W1L,
    unsigned short* __restrict__ WatTopH, unsigned short* __restrict__ WatTopL,
    unsigned short* __restrict__ WhhH, unsigned short* __restrict__ WhhL)
{
    int idx = blockIdx.x * 256 + threadIdx.x;
    if (idx < 768 * KPAD) {
        int n = idx / KPAD, k = idx % KPAD;
        float v = 0.f;
        if (k < 300) v = (n < 384) ? Wf[n * 300 + k] : Wb[(n - 384) * 300 + k];
        unsigned short h = f2bf(v);
        Bgt_hi[idx] = h;
        Bgt_lo[idx] = f2bf(v - bf2f(h));
    }
    if (idx < 768) bias_gi[idx] = (idx < 384) ? bf[idx] : bb[idx - 384];
    if (idx < 512 * 256) {
        int n = idx >> 8, k = idx & 255;
        Wswt[idx] = f2bf(Watt[(size_t)(256 + k) * 512 + n]);
        float v = Watt[(size_t)k * 512 + n];
        unsigned short h = f2bf(v);
        WatTopH[idx] = h;
        WatTopL[idx] = f2bf(v - bf2f(h));
    }
    if (idx < 128 * 512) {
        float v = W1[idx];
        unsigned short h = f2bf(v);
        W1H[idx] = h;
        W1L[idx] = f2bf(v - bf2f(h));
    }
    if (idx < 2 * 384 * 128) {   // Whh bf16 hi/lo, [dir][384][128] (== Bt rows)
        int dd = idx / 49152;
        int rest = idx - dd * 49152;
        const float* W = dd ? Whh_b : Whh_f;
        float v = W[rest];
        unsigned short h = f2bf(v);
        WhhH[idx] = h;
        WhhL[idx] = f2bf(v - bf2f(h));
    }
}

// ---------------- embedding mean -> bf16 hi/lo [8192][320] ----------------
__global__ __launch_bounds__(256) void embed_mean_kernel(
    const int* __restrict__ wids, const float* __restrict__ table,
    unsigned short* __restrict__ Ahi, unsigned short* __restrict__ Alo)
{
    int wv = (blockIdx.x << 2) + (threadIdx.x >> 6);
    int lane = threadIdx.x & 63;
    if (wv >= NROWS) return;
    const int* idp = wids + (size_t)wv * Wk;
    float4 a0 = {0,0,0,0}, a1 = {0,0,0,0};
    #pragma unroll 4
    for (int w = 0; w < Wk; ++w) {
        int id = idp[w];
        const float4* r4 = reinterpret_cast<const float4*>(table + (size_t)id * Ek);
        float4 v0 = r4[lane];
        a0.x += v0.x; a0.y += v0.y; a0.z += v0.z; a0.w += v0.w;
        if (lane < 11) {
            float4 v1 = r4[64 + lane];
            a1.x += v1.x; a1.y += v1.y; a1.z += v1.z; a1.w += v1.w;
        }
    }
    const float sc = 1.f / 32.f;
    unsigned short* hp = Ahi + (size_t)wv * KPAD;
    unsigned short* lp = Alo + (size_t)wv * KPAD;
    {
        float v[4] = {a0.x*sc, a0.y*sc, a0.z*sc, a0.w*sc};
        ushort4 h, l;
        h.x=f2bf(v[0]); h.y=f2bf(v[1]); h.z=f2bf(v[2]); h.w=f2bf(v[3]);
        l.x=f2bf(v[0]-bf2f(h.x)); l.y=f2bf(v[1]-bf2f(h.y));
        l.z=f2bf(v[2]-bf2f(h.z)); l.w=f2bf(v[3]-bf2f(h.w));
        *reinterpret_cast<ushort4*>(hp + lane*4) = h;
        *reinterpret_cast<ushort4*>(lp + lane*4) = l;
    }
    if (lane < 11) {
        float v[4] = {a1.x*sc, a1.y*sc, a1.z*sc, a1.w*sc};
        ushort4 h, l;
        h.x=f2bf(v[0]); h.y=f2bf(v[1]); h.z=f2bf(v[2]); h.w=f2bf(v[3]);
        l.x=f2bf(v[0]-bf2f(h.x)); l.y=f2bf(v[1]-bf2f(h.y));
        l.z=f2bf(v[2]-bf2f(h.z)); l.w=f2bf(v[3]-bf2f(h.w));
        *reinterpret_cast<ushort4*>(hp + 256 + lane*4) = h;
        *reinterpret_cast<ushort4*>(lp + 256 + lane*4) = l;
    } else if (lane < 16) {
        ushort4 z = {0,0,0,0};
        *reinterpret_cast<ushort4*>(hp + 256 + lane*4) = z;
        *reinterpret_cast<ushort4*>(lp + 256 + lane*4) = z;
    }
}

// ---------------- MFMA bf16 GEMM: C[M,N] = A @ Bt^T (+bias, relu) ---------
template<int PASSES, bool BIAS, bool RELU>
__global__ __launch_bounds__(256) void mfma_gemm_kernel(
    const unsigned short* __restrict__ Ahi, const unsigned short* __restrict__ Alo,
    const unsigned short* __restrict__ Bthi, const unsigned short* __restrict__ Btlo,
    const float* __restrict__ bias, float* __restrict__ C,
    int M, int N, int Kp)
{
    __shared__ unsigned short At_h[128][40];
    __shared__ unsigned short Bt_h[128][40];
    __shared__ unsigned short At_l[128][40];
    __shared__ unsigned short Bt_l[128][40];
    const int tid = threadIdx.x;
    const int m0 = blockIdx.x * 128, n0 = blockIdx.y * 128;
    const int lane = tid & 63;
    const int wave = tid >> 6;
    const int wr = (wave >> 1) * 64, wc = (wave & 1) * 64;
    const int l15 = lane & 15, l4 = lane >> 4;
    f32x4 acc[4][4] = {};

    const int srow = tid >> 1;
    const int scol = (tid & 1) * 16;

    for (int k0 = 0; k0 < Kp; k0 += 32) {
        {
            const unsigned short* ag = Ahi + (size_t)(m0 + srow) * Kp + k0 + scol;
            *reinterpret_cast<short8v*>(&At_h[srow][scol])     = *reinterpret_cast<const short8v*>(ag);
            *reinterpret_cast<short8v*>(&At_h[srow][scol + 8]) = *reinterpret_cast<const short8v*>(ag + 8);
            const unsigned short* bg = Bthi + (size_t)(n0 + srow) * Kp + k0 + scol;
            *reinterpret_cast<short8v*>(&Bt_h[srow][scol])     = *reinterpret_cast<const short8v*>(bg);
            *reinterpret_cast<short8v*>(&Bt_h[srow][scol + 8]) = *reinterpret_cast<const short8v*>(bg + 8);
            if (PASSES > 1) {
                const unsigned short* ag2 = Alo + (size_t)(m0 + srow) * Kp + k0 + scol;
                *reinterpret_cast<short8v*>(&At_l[srow][scol])     = *reinterpret_cast<const short8v*>(ag2);
                *reinterpret_cast<short8v*>(&At_l[srow][scol + 8]) = *reinterpret_cast<const short8v*>(ag2 + 8);
                const unsigned short* bg2 = Btlo + (size_t)(n0 + srow) * Kp + k0 + scol;
                *reinterpret_cast<short8v*>(&Bt_l[srow][scol])     = *reinterpret_cast<const short8v*>(bg2);
                *reinterpret_cast<short8v*>(&Bt_l[srow][scol + 8]) = *reinterpret_cast<const short8v*>(bg2 + 8);
            }
        }
        __syncthreads();
        short8v a_h[4], b_h[4], a_l[4], b_l[4];
        #pragma unroll
        for (int f = 0; f < 4; ++f) {
            a_h[f] = *reinterpret_cast<const short8v*>(&At_h[wr + f*16 + l15][l4*8]);
            b_h[f] = *reinterpret_cast<const short8v*>(&Bt_h[wc + f*16 + l15][l4*8]);
            if (PASSES > 1) {
                a_l[f] = *reinterpret_cast<const short8v*>(&At_l[wr + f*16 + l15][l4*8]);
                b_l[f] = *reinterpret_cast<const short8v*>(&Bt_l[wc + f*16 + l15][l4*8]);
            }
        }
        #pragma unroll
        for (int i = 0; i < 4; ++i) {
            #pragma unroll
            for (int j = 0; j < 4; ++j) {
                acc[i][j] = __builtin_amdgcn_mfma_f32_16x16x32_bf16(a_h[i], b_h[j], acc[i][j], 0, 0, 0);
                if (PASSES > 1) {
                    acc[i][j] = __builtin_amdgcn_mfma_f32_16x16x32_bf16(a_l[i], b_h[j], acc[i][j], 0, 0, 0);
                    acc[i][j] = __builtin_amdgcn_mfma_f32_16x16x32_bf16(a_h[i], b_l[j], acc[i][j], 0, 0, 0);
                }
            }
        }
        __syncthreads();
    }
    #pragma unroll
    for (int i = 0; i < 4; ++i) {
        #pragma unroll
        for (int j = 0; j < 4; ++j) {
            int col = n0 + wc + j * 16 + l15;
            float badd = BIAS ? bias[col] : 0.f;
            #pragma unroll
            for (int r = 0; r < 4; ++r) {
                int row = m0 + wr + i * 16 + l4 * 4 + r;
                float v = acc[i][j][r] + badd;
                if (RELU) v = fmaxf(v, 0.f);
                C[(size_t)row * N + col] = v;
            }
        }
    }
}

// ---------------- MFMA W1 GEMM with fused logits ---------------------------
__global__ __launch_bounds__(256) void mfma_w1_logits_kernel(
    const unsigned short* __restrict__ Ahi, const unsigned short* __restrict__ Alo,
    const unsigned short* __restrict__ Bthi, const unsigned short* __restrict__ Btlo,
    const float* __restrict__ b1, const float* __restrict__ W2,
    const float* __restrict__ b2, float* __restrict__ out)
{
    __shared__ unsigned short At_h[128][40];
    __shared__ unsigned short Bt_h[128][40];
    __shared__ unsigned short At_l[128][40];
    __shared__ unsigned short Bt_l[128][40];
    __shared__ float lpart[128];
    const int Kp = 512;
    const int tid = threadIdx.x;
    const int m0 = blockIdx.x * 128;
    const int lane = tid & 63;
    const int wave = tid >> 6;
    const int wr = (wave >> 1) * 64, wc = (wave & 1) * 64;
    const int l15 = lane & 15, l4 = lane >> 4;
    f32x4 acc[4][4] = {};

    const int srow = tid >> 1;
    const int scol = (tid & 1) * 16;

    for (int k0 = 0; k0 < Kp; k0 += 32) {
        {
            const unsigned short* ag = Ahi + (size_t)(m0 + srow) * Kp + k0 + scol;
            *reinterpret_cast<short8v*>(&At_h[srow][scol])     = *reinterpret_cast<const short8v*>(ag);
            *reinterpret_cast<short8v*>(&At_h[srow][scol + 8]) = *reinterpret_cast<const short8v*>(ag + 8);
            const unsigned short* bg = Bthi + (size_t)srow * Kp + k0 + scol;
            *reinterpret_cast<short8v*>(&Bt_h[srow][scol])     = *reinterpret_cast<const short8v*>(bg);
            *reinterpret_cast<short8v*>(&Bt_h[srow][scol + 8]) = *reinterpret_cast<const short8v*>(bg + 8);
            const unsigned short* ag2 = Alo + (size_t)(m0 + srow) * Kp + k0 + scol;
            *reinterpret_cast<short8v*>(&At_l[srow][scol])     = *reinterpret_cast<const short8v*>(ag2);
            *reinterpret_cast<short8v*>(&At_l[srow][scol + 8]) = *reinterpret_cast<const short8v*>(ag2 + 8);
            const unsigned short* bg2 = Btlo + (size_t)srow * Kp + k0 + scol;
            *reinterpret_cast<short8v*>(&Bt_l[srow][scol])     = *reinterpret_cast<const short8v*>(bg2);
            *reinterpret_cast<short8v*>(&Bt_l[srow][scol + 8]) = *reinterpret_cast<const short8v*>(bg2 + 8);
        }
        __syncthreads();
        short8v a_h[4], b_h[4], a_l[4], b_l[4];
        #pragma unroll
        for (int f = 0; f < 4; ++f) {
            a_h[f] = *reinterpret_cast<const short8v*>(&At_h[wr + f*16 + l15][l4*8]);
            b_h[f] = *reinterpret_cast<const short8v*>(&Bt_h[wc + f*16 + l15][l4*8]);
            a_l[f] = *reinterpret_cast<const short8v*>(&At_l[wr + f*16 + l15][l4*8]);
            b_l[f] = *reinterpret_cast<const short8v*>(&Bt_l[wc + f*16 + l15][l4*8]);
        }
        #pragma unroll
        for (int i = 0; i < 4; ++i) {
            #pragma unroll
            for (int j = 0; j < 4; ++j) {
                acc[i][j] = __builtin_amdgcn_mfma_f32_16x16x32_bf16(a_h[i], b_h[j], acc[i][j], 0, 0, 0);
                acc[i][j] = __builtin_amdgcn_mfma_f32_16x16x32_bf16(a_l[i], b_h[j], acc[i][j], 0, 0, 0);
                acc[i][j] = __builtin_amdgcn_mfma_f32_16x16x32_bf16(a_h[i], b_l[j], acc[i][j], 0, 0, 0);
            }
        }
        __syncthreads();
    }
    float b1v[4], w2v[4];
    #pragma unroll
    for (int j = 0; j < 4; ++j) {
        int col = wc + j * 16 + l15;
        b1v[j] = b1[col];
        w2v[j] = W2[col];
    }
    float lsum[4][4];
    #pragma unroll
    for (int i = 0; i < 4; ++i) {
        #pragma unroll
        for (int r = 0; r < 4; ++r) {
            float s = 0.f;
            #pragma unroll
            for (int j = 0; j < 4; ++j) {
                float v = fmaxf(acc[i][j][r] + b1v[j], 0.f);
                s = fmaf(v, w2v[j], s);
            }
            s += __shfl_xor(s, 1); s += __shfl_xor(s, 2);
            s += __shfl_xor(s, 4); s += __shfl_xor(s, 8);
            lsum[i][r] = s;
        }
    }
    if (wc == 0 && l15 == 0) {
        #pragma unroll
        for (int i = 0; i < 4; ++i)
            #pragma unroll
            for (int r = 0; r < 4; ++r)
                lpart[wr + i * 16 + l4 * 4 + r] = lsum[i][r];
    }
    __syncthreads();
    if (wc == 64 && l15 == 0) {
        float bb2 = b2[0];
        #pragma unroll
        for (int i = 0; i < 4; ++i)
            #pragma unroll
            for (int r = 0; r < 4; ++r) {
                int rl = wr + i * 16 + l4 * 4 + r;
                out[m0 + rl] = lpart[rl] + lsum[i][r] + bb2;
            }
    }
}

// ---------------- MFMA SW GEMM with fused attention scores ----------------
__global__ __launch_bounds__(256) void mfma_swscore_kernel(
    const unsigned short* __restrict__ Ahi, const unsigned short* __restrict__ Bthi,
    const float* __restrict__ dptp, const float* __restrict__ vatt,
    const int* __restrict__ tidmap,
    float* __restrict__ dscp, float* __restrict__ tscp)
{
    __shared__ unsigned short At_h[128][40];
    __shared__ unsigned short Bt_h[128][40];
    const int tid = threadIdx.x;
    const int m0 = blockIdx.x * 128, n0 = blockIdx.y * 128;
    const int Kp = 256;
    const int lane = tid & 63;
    const int wave = tid >> 6;
    const int wr = (wave >> 1) * 64, wc = (wave & 1) * 64;
    const int l15 = lane & 15, l4 = lane >> 4;
    f32x4 acc[4][4] = {};

    const int srow = tid >> 1;
    const int scol = (tid & 1) * 16;

    for (int k0 = 0; k0 < Kp; k0 += 32) {
        {
            const unsigned short* ag = Ahi + (size_t)(m0 + srow) * Kp + k0 + scol;
            *reinterpret_cast<short8v*>(&At_h[srow][scol])     = *reinterpret_cast<const short8v*>(ag);
            *reinterpret_cast<short8v*>(&At_h[srow][scol + 8]) = *reinterpret_cast<const short8v*>(ag + 8);
            const unsigned short* bg = Bthi + (size_t)(n0 + srow) * Kp + k0 + scol;
            *reinterpret_cast<short8v*>(&Bt_h[srow][scol])     = *reinterpret_cast<const short8v*>(bg);
            *reinterpret_cast<short8v*>(&Bt_h[srow][scol + 8]) = *reinterpret_cast<const short8v*>(bg + 8);
        }
        __syncthreads();
        short8v a_h[4], b_h[4];
        #pragma unroll
        for (int f = 0; f < 4; ++f) {
            a_h[f] = *reinterpret_cast<const short8v*>(&At_h[wr + f*16 + l15][l4*8]);
            b_h[f] = *reinterpret_cast<const short8v*>(&Bt_h[wc + f*16 + l15][l4*8]);
        }
        #pragma unroll
        for (int i = 0; i < 4; ++i)
            #pragma unroll
            for (int j = 0; j < 4; ++j)
                acc[i][j] = __builtin_amdgcn_mfma_f32_16x16x32_bf16(a_h[i], b_h[j], acc[i][j], 0, 0, 0);
        __syncthreads();
    }
    const int bb = m0 >> 8;
    const float* dpr = dptp + (size_t)bb * 512;
    float vv[4], dpv[4];
    #pragma unroll
    for (int j = 0; j < 4; ++j) {
        int col = n0 + wc + j * 16 + l15;
        vv[j] = vatt[col];
        dpv[j] = dpr[col];
    }
    const int slot = blockIdx.y * 2 + (wc >> 6);
    #pragma unroll
    for (int i = 0; i < 4; ++i) {
        #pragma unroll
        for (int r = 0; r < 4; ++r) {
            int row = m0 + wr + i * 16 + l4 * 4 + r;
            int ti = tidmap[row];
            const float* tpr = dptp + (size_t)(32 + bb * 16 + ti) * 512;
            float sd = 0.f, st = 0.f;
            #pragma unroll
            for (int j = 0; j < 4; ++j) {
                int col = n0 + wc + j * 16 + l15;
                float c = acc[i][j][r];
                sd += fast_tanh(c + dpv[j]) * vv[j];
                st += fast_tanh(c + tpr[col]) * vv[j];
            }
            sd += __shfl_xor(sd, 1); sd += __shfl_xor(sd, 2);
            sd += __shfl_xor(sd, 4); sd += __shfl_xor(sd, 8);
            st += __shfl_xor(st, 1); st += __shfl_xor(st, 2);
            st += __shfl_xor(st, 4); st += __shfl_xor(st, 8);
            if (l15 == 0) {
                dscp[(size_t)row * 8 + slot] = sd;
                tscp[(size_t)row * 8 + slot] = st;
            }
        }
    }
}

// ---------------- GRU scan (r12: MFMA engine) -----------------------------
// 4 blocks = (dir, half). Each block owns M=16 sequences; per step one
// MFMA GEMM M=16,N=384,K=128 (16x16x32_bf16, 3-pass split = fp32 accuracy).
// Wave w owns n-tiles {w, w+8, w+16} -> its lane's C col j=w*16+l15 carries
// r/z/n gates for the same (batch,j): gates need ZERO cross-lane traffic
// (the old shfl chains are gone). h_old kept in producer lane's registers.
// Whh persistent in VGPRs as B-fragments (96 regs). h redistributed via
// double-buffered LDS ([16][152] bf16 hi/lo, bank-spread), 1 barrier/step.
// gi fp32, depth-2 parity prefetch (unclamped; +-2-step spill lands in
// adjacent live ws regions, never consumed).
__global__ __launch_bounds__(512, 1) void gru_scan_mfma_kernel(
    const float* __restrict__ gi,
    const unsigned short* __restrict__ WhhH, const unsigned short* __restrict__ WhhL,
    const float* __restrict__ bhh_f, const float* __restrict__ bhh_b,
    float* __restrict__ sent_rep, unsigned short* __restrict__ srh,
    float* __restrict__ hT)
{
    const int dir  = blockIdx.x >> 1;
    const int half = blockIdx.x & 1;
    const int t = threadIdx.x;
    const int lane = t & 63;
    const int w = t >> 6;              // wave 0..7
    const int l15 = lane & 15, l4 = lane >> 4;
    const int j = w * 16 + l15;        // hidden/gate col 0..127
    const float* bhh = dir ? bhh_b : bhh_f;
    __shared__ unsigned short hls[2][2][16][152];   // [buf][hi/lo][batch][col padded]

    // persistent B fragments: gate g tile = g*8+w -> rows g*128 + j
    const unsigned short* WH = WhhH + (size_t)dir * 49152;
    const unsigned short* WL = WhhL + (size_t)dir * 49152;
    short8v bh0[4], bh1[4], bh2[4], bl0[4], bl1[4], bl2[4];
    #pragma unroll
    for (int kt = 0; kt < 4; ++kt) {
        const size_t ko = (size_t)kt * 32 + l4 * 8;
        bh0[kt] = *reinterpret_cast<const short8v*>(WH + (size_t)(0 * 128 + j) * 128 + ko);
        bh1[kt] = *reinterpret_cast<const short8v*>(WH + (size_t)(1 * 128 + j) * 128 + ko);
        bh2[kt] = *reinterpret_cast<const short8v*>(WH + (size_t)(2 * 128 + j) * 128 + ko);
        bl0[kt] = *reinterpret_cast<const short8v*>(WL + (size_t)(0 * 128 + j) * 128 + ko);
        bl1[kt] = *reinterpret_cast<const short8v*>(WL + (size_t)(1 * 128 + j) * 128 + ko);
        bl2[kt] = *reinterpret_cast<const short8v*>(WL + (size_t)(2 * 128 + j) * 128 + ko);
    }
    const float b_r = bhh[j], b_z = bhh[128 + j], b_n = bhh[256 + j];

    // zero both h buffers
    for (int i = t; i < 2 * 2 * 16 * 152; i += 512) ((unsigned short*)hls)[i] = 0;

    // gi prefetch (parity): giA even steps, giB odd
    float giA[12], giB[12];
    {
        const int s0 = dir ? (Sk - 1) : 0;
        const int s1 = dir ? (Sk - 2) : 1;
        #pragma unroll
        for (int r = 0; r < 4; ++r) {
            const int b = half * 16 + l4 * 4 + r;
            const float* g0 = gi + ((size_t)b * Sk + s0) * GI_N + dir * 384 + j;
            giA[3*r+0] = g0[0]; giA[3*r+1] = g0[128]; giA[3*r+2] = g0[256];
            const float* g1 = gi + ((size_t)b * Sk + s1) * GI_N + dir * 384 + j;
            giB[3*r+0] = g1[0]; giB[3*r+1] = g1[128]; giB[3*r+2] = g1[256];
        }
    }
    float hprev[4] = {0.f, 0.f, 0.f, 0.f};
    __syncthreads();

    int cur = 0;
    #define SSTEP(GIBUF, SEXPR) { \
        const int s = (SEXPR); \
        short8v ah[4], al[4]; \
        _Pragma("unroll") \
        for (int kt = 0; kt < 4; ++kt) { \
            ah[kt] = *reinterpret_cast<const short8v*>(&hls[cur][0][l15][kt*32 + l4*8]); \
            al[kt] = *reinterpret_cast<const short8v*>(&hls[cur][1][l15][kt*32 + l4*8]); \
        } \
        f32x4 accR = {}, accZ = {}, accN = {}; \
        _Pragma("unroll") \
        for (int kt = 0; kt < 4; ++kt) { \
            accR = __builtin_amdgcn_mfma_f32_16x16x32_bf16(ah[kt], bh0[kt], accR, 0, 0, 0); \
            accR = __builtin_amdgcn_mfma_f32_16x16x32_bf16(al[kt], bh0[kt], accR, 0, 0, 0); \
            accR = __builtin_amdgcn_mfma_f32_16x16x32_bf16(ah[kt], bl0[kt], accR, 0, 0, 0); \
            accZ = __builtin_amdgcn_mfma_f32_16x16x32_bf16(ah[kt], bh1[kt], accZ, 0, 0, 0); \
            accZ = __builtin_amdgcn_mfma_f32_16x16x32_bf16(al[kt], bh1[kt], accZ, 0, 0, 0); \
            accZ = __builtin_amdgcn_mfma_f32_16x16x32_bf16(ah[kt], bl1[kt], accZ, 0, 0, 0); \
            accN = __builtin_amdgcn_mfma_f32_16x16x32_bf16(ah[kt], bh2[kt], accN, 0, 0, 0); \
            accN = __builtin_amdgcn_mfma_f32_16x16x32_bf16(al[kt], bh2[kt], accN, 0, 0, 0); \
            accN = __builtin_amdgcn_mfma_f32_16x16x32_bf16(ah[kt], bl2[kt], accN, 0, 0, 0); \
        } \
        const int nxt = cur ^ 1; \
        _Pragma("unroll") \
        for (int r = 0; r < 4; ++r) { \
            float rr = fast_sigmoid(GIBUF[3*r+0] + accR[r] + b_r); \
            float zz = fast_sigmoid(GIBUF[3*r+1] + accZ[r] + b_z); \
            float nn = fast_tanh(GIBUF[3*r+2] + rr * (accN[r] + b_n)); \
            float hnew = (1.f - zz) * nn + zz * hprev[r]; \
            hprev[r] = hnew; \
            const size_t orow = ((size_t)(half*16 + l4*4 + r) * Sk + s); \
            sent_rep[orow * 256 + dir * 128 + j] = hnew; \
            srh[orow * 256 + dir * 128 + j] = f2bf(hnew); \
            unsigned short hh = f2bf(hnew); \
            hls[nxt][0][l4*4 + r][j] = hh; \
            hls[nxt][1][l4*4 + r][j] = f2bf(hnew - bf2f(hh)); \
            const long sn = dir ? (long)s - 2 : (long)s + 2; \
            const float* gp = gi + ((long)(half*16 + l4*4 + r) * Sk + sn) * GI_N + dir * 384 + j; \
            GIBUF[3*r+0] = gp[0]; GIBUF[3*r+1] = gp[128]; GIBUF[3*r+2] = gp[256]; \
        } \
        barrier_lgkm(); \
        cur ^= 1; \
    }

    for (int step = 0; step < Sk; step += 2) {
        SSTEP(giA, dir ? (Sk - 1 - step) : step);
        SSTEP(giB, dir ? (Sk - 2 - step) : (step + 1));
    }
    #undef SSTEP

    #pragma unroll
    for (int r = 0; r < 4; ++r)
        hT[dir * 4096 + (half * 16 + l4 * 4 + r) * 128 + j] = hprev[r];
}

// ---------------- prep: doc_vec + topic_mat + tidmap (fused) --------------
__device__ __forceinline__ float4 sr_load_guard(const float* sr, int b, int sidx, int j4) {
    if (sidx < 0 || sidx >= Sk) { float4 z = {0,0,0,0}; return z; }
    return reinterpret_cast<const float4*>(sr)[(size_t)(b * Sk + sidx) * 64 + j4];
}
__global__ __launch_bounds__(64) void prep_kernel(
    const int* __restrict__ tse, const float* __restrict__ sent_rep,
    const float* __restrict__ hT, float* __restrict__ dvtm,
    unsigned short* __restrict__ dvtmH, unsigned short* __restrict__ dvtmL,
    int* __restrict__ tidmap)
{
    const int b = blockIdx.x;
    const int t = blockIdx.y;
    const int j4 = threadIdx.x;
    float4 v;
    int row;
    if (t == 16) {
        int dir = b >> 4;
        int bb = 2 * (b & 15) + (j4 >> 5);
        int jj4 = j4 & 31;
        v = reinterpret_cast<const float4*>(hT)[dir * 1024 + bb * 32 + jj4];
        row = b;
        for (int ss = j4; ss < 256; ss += 64) {
            int ti = 0;
            #pragma unroll
            for (int tt = 1; tt < 16; ++tt) ti += (ss >= tse[b * 32 + tt * 2] - 1) ? 1 : 0;
            tidmap[b * 256 + ss] = ti;
        }
    } else {
        int st = tse[b * 32 + t * 2];
        int en = tse[b * 32 + t * 2 + 1];
        float4 va, vb;
        if (j4 < 32) {
            va = sr_load_guard(sent_rep, b, en - 1, j4);
            vb = sr_load_guard(sent_rep, b, st - 2, j4);
        } else {
            va = sr_load_guard(sent_rep, b, st - 1, j4);
            vb = sr_load_guard(sent_rep, b, en, j4);
        }
        v.x = va.x - vb.x; v.y = va.y - vb.y; v.z = va.z - vb.z; v.w = va.w - vb.w;
        row = 32 + b * 16 + t;
    }
    reinterpret_cast<float4*>(dvtm)[row * 64 + j4] = v;
    ushort4 h, l;
    h.x = f2bf(v.x); h.y = f2bf(v.y); h.z = f2bf(v.z); h.w = f2bf(v.w);
    l.x = f2bf(v.x - bf2f(h.x)); l.y = f2bf(v.y - bf2f(h.y));
    l.z = f2bf(v.z - bf2f(h.z)); l.w = f2bf(v.w - bf2f(h.w));
    *reinterpret_cast<ushort4*>(dvtmH + (size_t)row * 256 + j4 * 4) = h;
    *reinterpret_cast<ushort4*>(dvtmL + (size_t)row * 256 + j4 * 4) = l;
}

// ---------------- softmax (sums partials, outputs weights) ----------------
__global__ __launch_bounds__(256) void softmax_kernel(
    const float* __restrict__ dscp, const float* __restrict__ tscp,
    float* __restrict__ dsc, float* __restrict__ tsc)
{
    const int b = blockIdx.x, sidx = threadIdx.x;
    const int lane = sidx & 63, wid = sidx >> 6;
    __shared__ float rd[4], rt[4];
    const float4* dp8 = reinterpret_cast<const float4*>(dscp + (size_t)(b * Sk + sidx) * 8);
    const float4* tp8 = reinterpret_cast<const float4*>(tscp + (size_t)(b * Sk + sidx) * 8);
    float4 d0 = dp8[0], d1 = dp8[1], t0 = tp8[0], t1 = tp8[1];
    float d = ((d0.x + d0.y) + (d0.z + d0.w)) + ((d1.x + d1.y) + (d1.z + d1.w));
    float t = ((t0.x + t0.y) + (t0.z + t0.w)) + ((t1.x + t1.y) + (t1.z + t1.w));
    float md = d, mt = t;
    #pragma unroll
    for (int off = 32; off; off >>= 1) {
        md = fmaxf(md, __shfl_xor(md, off));
        mt = fmaxf(mt, __shfl_xor(mt, off));
    }
    if (lane == 0) { rd[wid] = md; rt[wid] = mt; }
    __syncthreads();
    md = fmaxf(fmaxf(rd[0], rd[1]), fmaxf(rd[2], rd[3]));
    mt = fmaxf(fmaxf(rt[0], rt[1]), fmaxf(rt[2], rt[3]));
    float ed = __expf(d - md), et = __expf(t - mt);
    float sd = ed, stt = et;
    #pragma unroll
    for (int off = 32; off; off >>= 1) {
        sd += __shfl_xor(sd, off);
        stt += __shfl_xor(stt, off);
    }
    __syncthreads();
    if (lane == 0) { rd[wid] = sd; rt[wid] = stt; }
    __syncthreads();
    sd = rd[0] + rd[1] + rd[2] + rd[3];
    stt = rt[0] + rt[1] + rt[2] + rt[3];
    dsc[b * Sk + sidx] = ed / sd;
    tsc[b * Sk + sidx] = et / stt;
}

// ---------------- build inp (bf16 hi/lo) = [sent_rep, context] ------------
__global__ __launch_bounds__(128) void build_inp_kernel(
    const float* __restrict__ sent_rep, const float* __restrict__ dvtm,
    const float* __restrict__ dw, const float* __restrict__ tw,
    const int* __restrict__ tidmap,
    unsigned short* __restrict__ inpH, unsigned short* __restrict__ inpL)
{
    int row = blockIdx.x;
    int b = row >> 8;
    int f4c = threadIdx.x;
    float4 v;
    if (f4c < 64) {
        v = reinterpret_cast<const float4*>(sent_rep)[(size_t)row * 64 + f4c];
    } else {
        int ti = tidmap[row];
        float dwv = dw[row], twv = tw[row];
        int j4 = f4c - 64;
        float4 dv = reinterpret_cast<const float4*>(dvtm)[b * 64 + j4];
        float4 tm = reinterpret_cast<const float4*>(dvtm)[(32 + b * 16 + ti) * 64 + j4];
        v.x = dwv * dv.x + twv * tm.x;
        v.y = dwv * dv.y + twv * tm.y;
        v.z = dwv * dv.z + twv * tm.z;
        v.w = dwv * dv.w + twv * tm.w;
    }
    ushort4 h, l;
    h.x = f2bf(v.x); h.y = f2bf(v.y); h.z = f2bf(v.z); h.w = f2bf(v.w);
    l.x = f2bf(v.x - bf2f(h.x)); l.y = f2bf(v.y - bf2f(h.y));
    l.z = f2bf(v.z - bf2f(h.z)); l.w = f2bf(v.w - bf2f(h.w));
    *reinterpret_cast<ushort4*>(inpH + (size_t)row * 512 + f4c * 4) = h;
    *reinterpret_cast<ushort4*>(inpL + (size_t)row * 512 + f4c * 4) = l;
}

// ---------------- launch ----------------
extern "C" void kernel_launch(void* const* d_in, const int* in_sizes, int n_in,
                              void* d_out, int out_size, void* d_ws, size_t ws_size,
                              hipStream_t stream)
{
    const int*   wids  = (const int*)d_in[0];
    const int*   tse   = (const int*)d_in[1];
    const float* table = (const float*)d_in[2];
    const float* Wihf  = (const float*)d_in[3];
    const float* Whhf  = (const float*)d_in[4];
    const float* bihf  = (const float*)d_in[5];
    const float* bhhf  = (const float*)d_in[6];
    const float* Wihb  = (const float*)d_in[7];
    const float* Whhb  = (const float*)d_in[8];
    const float* bihb  = (const float*)d_in[9];
    const float* bhhb  = (const float*)d_in[10];
    const float* vatt  = (const float*)d_in[11];
    const float* Watt  = (const float*)d_in[12];
    const float* W1    = (const float*)d_in[13];
    const float* b1    = (const float*)d_in[14];
    const float* W2    = (const float*)d_in[15];
    const float* b2    = (const float*)d_in[16];
    float* ws = (float*)d_ws;
    float* out = (float*)d_out;

    // layout (float units)
    unsigned short* Ahi   = (unsigned short*)(ws + 0);          // 1,310,720 f
    unsigned short* Alo   = (unsigned short*)(ws + 1310720);    // 1,310,720 f
    float* gi             = ws + 2621440;                       // 6,291,456
    float* sent_rep       = ws + 8912896;                       // 2,097,152
    unsigned short* SRhi  = (unsigned short*)(ws + 11010048);   // 1,048,576 f
    float* hT             = ws + 12058624;                      // 8,192
    float* dvtm           = ws + 12066816;                      // 139,264
    float* dptp           = ws + 12206080;                      // 327,680 (640x512)
    float* dsc            = ws + 12533760;                      // 8,192
    float* tsc            = ws + 12541952;                      // 8,192
    unsigned short* BgtH  = (unsigned short*)(ws + 12550144);   // 122,880 f
    unsigned short* BgtL  = (unsigned short*)(ws + 12673024);   // 122,880 f
    float* bias_gi        = ws + 12795904;                      // 768
    unsigned short* Wswt  = (unsigned short*)(ws + 12796672);   // 65,536 f
    unsigned short* W1H   = (unsigned short*)(ws + 12862208);   // 32,768 f
    unsigned short* W1L   = (unsigned short*)(ws + 12894976);   // 32,768 f
    float* dscp           = ws + 12927744;                      // 65,536
    float* tscp           = ws + 12993280;                      // 65,536
    int*   tidmap         = (int*)(ws + 13058816);              // 8,192
    unsigned short* dvtmH = (unsigned short*)(ws + 13067008);   // 81,920 f
    unsigned short* dvtmL = (unsigned short*)(ws + 13148928);   // 81,920 f
    unsigned short* WatTH = (unsigned short*)(ws + 13230848);   // 65,536 f
    unsigned short* WatTL = (unsigned short*)(ws + 13296384);   // 65,536 f
    unsigned short* WhhHp = (unsigned short*)(ws + 13361920);   // 49,152 f
    unsigned short* WhhLp = (unsigned short*)(ws + 13411072);   // 49,152 f
    // end 13,460,224 floats
    // dead-zone reuse (Ahi/Alo/gi dead after scan):
    unsigned short* inpH  = (unsigned short*)(ws + 0);          // 2,097,152 f
    unsigned short* inpL  = (unsigned short*)(ws + 2097152);    // 2,097,152 f

    if (ws_size < (size_t)13460224 * sizeof(float)) return;

    pack_kernel<<<960, 256, 0, stream>>>(Wihf, Wihb, Whhf, Whhb, bihf, bihb,
                                         Watt, W1, BgtH, BgtL, bias_gi, Wswt,
                                         W1H, W1L, WatTH, WatTL, WhhHp, WhhLp);
    embed_mean_kernel<<<2048, 256, 0, stream>>>(wids, table, Ahi, Alo);
    mfma_gemm_kernel<3, true, false><<<dim3(64, 6), 256, 0, stream>>>(
        Ahi, Alo, BgtH, BgtL, bias_gi, gi, NROWS, 768, KPAD);
    gru_scan_mfma_kernel<<<4, 512, 0, stream>>>(gi, WhhHp, WhhLp, bhhf, bhhb,
                                                sent_rep, SRhi, hT);
    prep_kernel<<<dim3(32, 17), 64, 0, stream>>>(tse, sent_rep, hT, dvtm,
                                                 dvtmH, dvtmL, tidmap);
    mfma_gemm_kernel<3, false, false><<<dim3(5, 4), 256, 0, stream>>>(
        dvtmH, dvtmL, WatTH, WatTL, nullptr, dptp, 640, 512, 256);
    mfma_swscore_kernel<<<dim3(64, 4), 256, 0, stream>>>(
        SRhi, Wswt, dptp, vatt, tidmap, dscp, tscp);
    softmax_kernel<<<32, 256, 0, stream>>>(dscp, tscp, dsc, tsc);
    build_inp_kernel<<<NROWS, 128, 0, stream>>>(sent_rep, dvtm, dsc, tsc, tidmap, inpH, inpL);
    mfma_w1_logits_kernel<<<dim3(64, 1), 256, 0, stream>>>(
        inpH, inpL, W1H, W1L, b1, W2, b2, out);
}

// Round 13
// 369.539 us; speedup vs baseline: 1.5253x; 1.5253x over previous
//
#include <hip/hip_runtime.h>
#include <hip/hip_bf16.h>
#include <cstdint>

// Problem constants
#define Bk 32
#define Sk 256
#define Wk 32
#define Tk 16
#define Ek 300
#define Hk 128
#define Dk 128
#define NROWS (Bk*Sk)          // 8192
#define GI_N  (3*Hk*2)         // 768
#define KPAD  320              // 300 padded to multiple of 32

typedef __attribute__((ext_vector_type(8))) short short8v;
typedef __attribute__((ext_vector_type(4))) float f32x4;

// ---------------- helpers ----------------
__device__ __forceinline__ float fast_sigmoid(float x) {
    return 1.f / (1.f + __expf(-x));
}
__device__ __forceinline__ float fast_tanh(float x) {
    float ax = fabsf(x);
    float e = __expf(2.f * ax);
    float t = 1.f - 2.f / (1.f + e);
    return copysignf(t, x);
}
__device__ __forceinline__ void barrier_lgkm() {
    asm volatile("s_waitcnt lgkmcnt(0)" ::: "memory");
    __builtin_amdgcn_s_barrier();
}
// fp32 -> bf16 (RNE), finite inputs
__device__ __forceinline__ unsigned short f2bf(float f) {
    uint32_t u = __float_as_uint(f);
    uint32_t r = (u + 0x7FFFu + ((u >> 16) & 1u)) >> 16;
    return (unsigned short)r;
}
__device__ __forceinline__ float bf2f(unsigned short h) {
    return __uint_as_float(((uint32_t)h) << 16);
}

// ---------------- pack kernel ----------------
__global__ __launch_bounds__(256) void pack_kernel(
    const float* __restrict__ Wf, const float* __restrict__ Wb,
    const float* __restrict__ Whh_f, const float* __restrict__ Whh_b,
    const float* __restrict__ bf, const float* __restrict__ bb,
    const float* __restrict__ Watt, const float* __restrict__ W1,
    unsigned short* __restrict__ Bgt_hi, unsigned short* __restrict__ Bgt_lo,
    float* __restrict__ bias_gi, unsigned short* __restrict__ Wswt,
    unsigned short* __restrict__ W1H, unsigned short* __restrict__ W1L,
    unsigned short* __restrict__ WatTopH, unsigned short* __restrict__ WatTopL,
    unsigned short* __restrict__ WhhH, unsigned short* __restrict__ WhhL)
{
    int idx = blockIdx.x * 256 + threadIdx.x;
    if (idx < 768 * KPAD) {
        int n = idx / KPAD, k = idx % KPAD;
        float v = 0.f;
        if (k < 300) v = (n < 384) ? Wf[n * 300 + k] : Wb[(n - 384) * 300 + k];
        unsigned short h = f2bf(v);
        Bgt_hi[idx] = h;
        Bgt_lo[idx] = f2bf(v - bf2f(h));
    }
    if (idx < 768) bias_gi[idx] = (idx < 384) ? bf[idx] : bb[idx - 384];
    if (idx < 512 * 256) {
        int n = idx >> 8, k = idx & 255;
        Wswt[idx] = f2bf(Watt[(size_t)(256 + k) * 512 + n]);
        float v = Watt[(size_t)k * 512 + n];
        unsigned short h = f2bf(v);
        WatTopH[idx] = h;
        WatTopL[idx] = f2bf(v - bf2f(h));
    }
    if (idx < 128 * 512) {
        float v = W1[idx];
        unsigned short h = f2bf(v);
        W1H[idx] = h;
        W1L[idx] = f2bf(v - bf2f(h));
    }
    if (idx < 2 * 384 * 128) {   // Whh bf16 hi/lo, [dir][384][128] (Bt rows)
        int dd = idx / 49152;
        int rest = idx - dd * 49152;
        const float* W = dd ? Whh_b : Whh_f;
        float v = W[rest];
        unsigned short h = f2bf(v);
        WhhH[idx] = h;
        WhhL[idx] = f2bf(v - bf2f(h));
    }
}

// ---------------- embedding mean -> bf16 hi/lo [8192][320] ----------------
__global__ __launch_bounds__(256) void embed_mean_kernel(
    const int* __restrict__ wids, const float* __restrict__ table,
    unsigned short* __restrict__ Ahi, unsigned short* __restrict__ Alo)
{
    int wv = (blockIdx.x << 2) + (threadIdx.x >> 6);
    int lane = threadIdx.x & 63;
    if (wv >= NROWS) return;
    const int* idp = wids + (size_t)wv * Wk;
    float4 a0 = {0,0,0,0}, a1 = {0,0,0,0};
    #pragma unroll 4
    for (int w = 0; w < Wk; ++w) {
        int id = idp[w];
        const float4* r4 = reinterpret_cast<const float4*>(table + (size_t)id * Ek);
        float4 v0 = r4[lane];
        a0.x += v0.x; a0.y += v0.y; a0.z += v0.z; a0.w += v0.w;
        if (lane < 11) {
            float4 v1 = r4[64 + lane];
            a1.x += v1.x; a1.y += v1.y; a1.z += v1.z; a1.w += v1.w;
        }
    }
    const float sc = 1.f / 32.f;
    unsigned short* hp = Ahi + (size_t)wv * KPAD;
    unsigned short* lp = Alo + (size_t)wv * KPAD;
    {
        float v[4] = {a0.x*sc, a0.y*sc, a0.z*sc, a0.w*sc};
        ushort4 h, l;
        h.x=f2bf(v[0]); h.y=f2bf(v[1]); h.z=f2bf(v[2]); h.w=f2bf(v[3]);
        l.x=f2bf(v[0]-bf2f(h.x)); l.y=f2bf(v[1]-bf2f(h.y));
        l.z=f2bf(v[2]-bf2f(h.z)); l.w=f2bf(v[3]-bf2f(h.w));
        *reinterpret_cast<ushort4*>(hp + lane*4) = h;
        *reinterpret_cast<ushort4*>(lp + lane*4) = l;
    }
    if (lane < 11) {
        float v[4] = {a1.x*sc, a1.y*sc, a1.z*sc, a1.w*sc};
        ushort4 h, l;
        h.x=f2bf(v[0]); h.y=f2bf(v[1]); h.z=f2bf(v[2]); h.w=f2bf(v[3]);
        l.x=f2bf(v[0]-bf2f(h.x)); l.y=f2bf(v[1]-bf2f(h.y));
        l.z=f2bf(v[2]-bf2f(h.z)); l.w=f2bf(v[3]-bf2f(h.w));
        *reinterpret_cast<ushort4*>(hp + 256 + lane*4) = h;
        *reinterpret_cast<ushort4*>(lp + 256 + lane*4) = l;
    } else if (lane < 16) {
        ushort4 z = {0,0,0,0};
        *reinterpret_cast<ushort4*>(hp + 256 + lane*4) = z;
        *reinterpret_cast<ushort4*>(lp + 256 + lane*4) = z;
    }
}

// ---------------- MFMA bf16 GEMM: C[M,N] = A @ Bt^T (+bias, relu) ---------
template<int PASSES, bool BIAS, bool RELU>
__global__ __launch_bounds__(256) void mfma_gemm_kernel(
    const unsigned short* __restrict__ Ahi, const unsigned short* __restrict__ Alo,
    const unsigned short* __restrict__ Bthi, const unsigned short* __restrict__ Btlo,
    const float* __restrict__ bias, float* __restrict__ C,
    int M, int N, int Kp)
{
    __shared__ unsigned short At_h[128][40];
    __shared__ unsigned short Bt_h[128][40];
    __shared__ unsigned short At_l[128][40];
    __shared__ unsigned short Bt_l[128][40];
    const int tid = threadIdx.x;
    const int m0 = blockIdx.x * 128, n0 = blockIdx.y * 128;
    const int lane = tid & 63;
    const int wave = tid >> 6;
    const int wr = (wave >> 1) * 64, wc = (wave & 1) * 64;
    const int l15 = lane & 15, l4 = lane >> 4;
    f32x4 acc[4][4] = {};

    const int srow = tid >> 1;
    const int scol = (tid & 1) * 16;

    for (int k0 = 0; k0 < Kp; k0 += 32) {
        {
            const unsigned short* ag = Ahi + (size_t)(m0 + srow) * Kp + k0 + scol;
            *reinterpret_cast<short8v*>(&At_h[srow][scol])     = *reinterpret_cast<const short8v*>(ag);
            *reinterpret_cast<short8v*>(&At_h[srow][scol + 8]) = *reinterpret_cast<const short8v*>(ag + 8);
            const unsigned short* bg = Bthi + (size_t)(n0 + srow) * Kp + k0 + scol;
            *reinterpret_cast<short8v*>(&Bt_h[srow][scol])     = *reinterpret_cast<const short8v*>(bg);
            *reinterpret_cast<short8v*>(&Bt_h[srow][scol + 8]) = *reinterpret_cast<const short8v*>(bg + 8);
            if (PASSES > 1) {
                const unsigned short* ag2 = Alo + (size_t)(m0 + srow) * Kp + k0 + scol;
                *reinterpret_cast<short8v*>(&At_l[srow][scol])     = *reinterpret_cast<const short8v*>(ag2);
                *reinterpret_cast<short8v*>(&At_l[srow][scol + 8]) = *reinterpret_cast<const short8v*>(ag2 + 8);
                const unsigned short* bg2 = Btlo + (size_t)(n0 + srow) * Kp + k0 + scol;
                *reinterpret_cast<short8v*>(&Bt_l[srow][scol])     = *reinterpret_cast<const short8v*>(bg2);
                *reinterpret_cast<short8v*>(&Bt_l[srow][scol + 8]) = *reinterpret_cast<const short8v*>(bg2 + 8);
            }
        }
        __syncthreads();
        short8v a_h[4], b_h[4], a_l[4], b_l[4];
        #pragma unroll
        for (int f = 0; f < 4; ++f) {
            a_h[f] = *reinterpret_cast<const short8v*>(&At_h[wr + f*16 + l15][l4*8]);
            b_h[f] = *reinterpret_cast<const short8v*>(&Bt_h[wc + f*16 + l15][l4*8]);
            if (PASSES > 1) {
                a_l[f] = *reinterpret_cast<const short8v*>(&At_l[wr + f*16 + l15][l4*8]);
                b_l[f] = *reinterpret_cast<const short8v*>(&Bt_l[wc + f*16 + l15][l4*8]);
            }
        }
        #pragma unroll
        for (int i = 0; i < 4; ++i) {
            #pragma unroll
            for (int j = 0; j < 4; ++j) {
                acc[i][j] = __builtin_amdgcn_mfma_f32_16x16x32_bf16(a_h[i], b_h[j], acc[i][j], 0, 0, 0);
                if (PASSES > 1) {
                    acc[i][j] = __builtin_amdgcn_mfma_f32_16x16x32_bf16(a_l[i], b_h[j], acc[i][j], 0, 0, 0);
                    acc[i][j] = __builtin_amdgcn_mfma_f32_16x16x32_bf16(a_h[i], b_l[j], acc[i][j], 0, 0, 0);
                }
            }
        }
        __syncthreads();
    }
    #pragma unroll
    for (int i = 0; i < 4; ++i) {
        #pragma unroll
        for (int j = 0; j < 4; ++j) {
            int col = n0 + wc + j * 16 + l15;
            float badd = BIAS ? bias[col] : 0.f;
            #pragma unroll
            for (int r = 0; r < 4; ++r) {
                int row = m0 + wr + i * 16 + l4 * 4 + r;
                float v = acc[i][j][r] + badd;
                if (RELU) v = fmaxf(v, 0.f);
                C[(size_t)row * N + col] = v;
            }
        }
    }
}

// ---------------- MFMA W1 GEMM with fused logits ---------------------------
__global__ __launch_bounds__(256) void mfma_w1_logits_kernel(
    const unsigned short* __restrict__ Ahi, const unsigned short* __restrict__ Alo,
    const unsigned short* __restrict__ Bthi, const unsigned short* __restrict__ Btlo,
    const float* __restrict__ b1, const float* __restrict__ W2,
    const float* __restrict__ b2, float* __restrict__ out)
{
    __shared__ unsigned short At_h[128][40];
    __shared__ unsigned short Bt_h[128][40];
    __shared__ unsigned short At_l[128][40];
    __shared__ unsigned short Bt_l[128][40];
    __shared__ float lpart[128];
    const int Kp = 512;
    const int tid = threadIdx.x;
    const int m0 = blockIdx.x * 128;
    const int lane = tid & 63;
    const int wave = tid >> 6;
    const int wr = (wave >> 1) * 64, wc = (wave & 1) * 64;
    const int l15 = lane & 15, l4 = lane >> 4;
    f32x4 acc[4][4] = {};

    const int srow = tid >> 1;
    const int scol = (tid & 1) * 16;

    for (int k0 = 0; k0 < Kp; k0 += 32) {
        {
            const unsigned short* ag = Ahi + (size_t)(m0 + srow) * Kp + k0 + scol;
            *reinterpret_cast<short8v*>(&At_h[srow][scol])     = *reinterpret_cast<const short8v*>(ag);
            *reinterpret_cast<short8v*>(&At_h[srow][scol + 8]) = *reinterpret_cast<const short8v*>(ag + 8);
            const unsigned short* bg = Bthi + (size_t)srow * Kp + k0 + scol;
            *reinterpret_cast<short8v*>(&Bt_h[srow][scol])     = *reinterpret_cast<const short8v*>(bg);
            *reinterpret_cast<short8v*>(&Bt_h[srow][scol + 8]) = *reinterpret_cast<const short8v*>(bg + 8);
            const unsigned short* ag2 = Alo + (size_t)(m0 + srow) * Kp + k0 + scol;
            *reinterpret_cast<short8v*>(&At_l[srow][scol])     = *reinterpret_cast<const short8v*>(ag2);
            *reinterpret_cast<short8v*>(&At_l[srow][scol + 8]) = *reinterpret_cast<const short8v*>(ag2 + 8);
            const unsigned short* bg2 = Btlo + (size_t)srow * Kp + k0 + scol;
            *reinterpret_cast<short8v*>(&Bt_l[srow][scol])     = *reinterpret_cast<const short8v*>(bg2);
            *reinterpret_cast<short8v*>(&Bt_l[srow][scol + 8]) = *reinterpret_cast<const short8v*>(bg2 + 8);
        }
        __syncthreads();
        short8v a_h[4], b_h[4], a_l[4], b_l[4];
        #pragma unroll
        for (int f = 0; f < 4; ++f) {
            a_h[f] = *reinterpret_cast<const short8v*>(&At_h[wr + f*16 + l15][l4*8]);
            b_h[f] = *reinterpret_cast<const short8v*>(&Bt_h[wc + f*16 + l15][l4*8]);
            a_l[f] = *reinterpret_cast<const short8v*>(&At_l[wr + f*16 + l15][l4*8]);
            b_l[f] = *reinterpret_cast<const short8v*>(&Bt_l[wc + f*16 + l15][l4*8]);
        }
        #pragma unroll
        for (int i = 0; i < 4; ++i) {
            #pragma unroll
            for (int j = 0; j < 4; ++j) {
                acc[i][j] = __builtin_amdgcn_mfma_f32_16x16x32_bf16(a_h[i], b_h[j], acc[i][j], 0, 0, 0);
                acc[i][j] = __builtin_amdgcn_mfma_f32_16x16x32_bf16(a_l[i], b_h[j], acc[i][j], 0, 0, 0);
                acc[i][j] = __builtin_amdgcn_mfma_f32_16x16x32_bf16(a_h[i], b_l[j], acc[i][j], 0, 0, 0);
            }
        }
        __syncthreads();
    }
    float b1v[4], w2v[4];
    #pragma unroll
    for (int j = 0; j < 4; ++j) {
        int col = wc + j * 16 + l15;
        b1v[j] = b1[col];
        w2v[j] = W2[col];
    }
    float lsum[4][4];
    #pragma unroll
    for (int i = 0; i < 4; ++i) {
        #pragma unroll
        for (int r = 0; r < 4; ++r) {
            float s = 0.f;
            #pragma unroll
            for (int j = 0; j < 4; ++j) {
                float v = fmaxf(acc[i][j][r] + b1v[j], 0.f);
                s = fmaf(v, w2v[j], s);
            }
            s += __shfl_xor(s, 1); s += __shfl_xor(s, 2);
            s += __shfl_xor(s, 4); s += __shfl_xor(s, 8);
            lsum[i][r] = s;
        }
    }
    if (wc == 0 && l15 == 0) {
        #pragma unroll
        for (int i = 0; i < 4; ++i)
            #pragma unroll
            for (int r = 0; r < 4; ++r)
                lpart[wr + i * 16 + l4 * 4 + r] = lsum[i][r];
    }
    __syncthreads();
    if (wc == 64 && l15 == 0) {
        float bb2 = b2[0];
        #pragma unroll
        for (int i = 0; i < 4; ++i)
            #pragma unroll
            for (int r = 0; r < 4; ++r) {
                int rl = wr + i * 16 + l4 * 4 + r;
                out[m0 + rl] = lpart[rl] + lsum[i][r] + bb2;
            }
    }
}

// ---------------- MFMA SW GEMM with fused attention scores ----------------
__global__ __launch_bounds__(256) void mfma_swscore_kernel(
    const unsigned short* __restrict__ Ahi, const unsigned short* __restrict__ Bthi,
    const float* __restrict__ dptp, const float* __restrict__ vatt,
    const int* __restrict__ tidmap,
    float* __restrict__ dscp, float* __restrict__ tscp)
{
    __shared__ unsigned short At_h[128][40];
    __shared__ unsigned short Bt_h[128][40];
    const int tid = threadIdx.x;
    const int m0 = blockIdx.x * 128, n0 = blockIdx.y * 128;
    const int Kp = 256;
    const int lane = tid & 63;
    const int wave = tid >> 6;
    const int wr = (wave >> 1) * 64, wc = (wave & 1) * 64;
    const int l15 = lane & 15, l4 = lane >> 4;
    f32x4 acc[4][4] = {};

    const int srow = tid >> 1;
    const int scol = (tid & 1) * 16;

    for (int k0 = 0; k0 < Kp; k0 += 32) {
        {
            const unsigned short* ag = Ahi + (size_t)(m0 + srow) * Kp + k0 + scol;
            *reinterpret_cast<short8v*>(&At_h[srow][scol])     = *reinterpret_cast<const short8v*>(ag);
            *reinterpret_cast<short8v*>(&At_h[srow][scol + 8]) = *reinterpret_cast<const short8v*>(ag + 8);
            const unsigned short* bg = Bthi + (size_t)(n0 + srow) * Kp + k0 + scol;
            *reinterpret_cast<short8v*>(&Bt_h[srow][scol])     = *reinterpret_cast<const short8v*>(bg);
            *reinterpret_cast<short8v*>(&Bt_h[srow][scol + 8]) = *reinterpret_cast<const short8v*>(bg + 8);
        }
        __syncthreads();
        short8v a_h[4], b_h[4];
        #pragma unroll
        for (int f = 0; f < 4; ++f) {
            a_h[f] = *reinterpret_cast<const short8v*>(&At_h[wr + f*16 + l15][l4*8]);
            b_h[f] = *reinterpret_cast<const short8v*>(&Bt_h[wc + f*16 + l15][l4*8]);
        }
        #pragma unroll
        for (int i = 0; i < 4; ++i)
            #pragma unroll
            for (int j = 0; j < 4; ++j)
                acc[i][j] = __builtin_amdgcn_mfma_f32_16x16x32_bf16(a_h[i], b_h[j], acc[i][j], 0, 0, 0);
        __syncthreads();
    }
    const int bb = m0 >> 8;
    const float* dpr = dptp + (size_t)bb * 512;
    float vv[4], dpv[4];
    #pragma unroll
    for (int j = 0; j < 4; ++j) {
        int col = n0 + wc + j * 16 + l15;
        vv[j] = vatt[col];
        dpv[j] = dpr[col];
    }
    const int slot = blockIdx.y * 2 + (wc >> 6);
    #pragma unroll
    for (int i = 0; i < 4; ++i) {
        #pragma unroll
        for (int r = 0; r < 4; ++r) {
            int row = m0 + wr + i * 16 + l4 * 4 + r;
            int ti = tidmap[row];
            const float* tpr = dptp + (size_t)(32 + bb * 16 + ti) * 512;
            float sd = 0.f, st = 0.f;
            #pragma unroll
            for (int j = 0; j < 4; ++j) {
                int col = n0 + wc + j * 16 + l15;
                float c = acc[i][j][r];
                sd += fast_tanh(c + dpv[j]) * vv[j];
                st += fast_tanh(c + tpr[col]) * vv[j];
            }
            sd += __shfl_xor(sd, 1); sd += __shfl_xor(sd, 2);
            sd += __shfl_xor(sd, 4); sd += __shfl_xor(sd, 8);
            st += __shfl_xor(st, 1); st += __shfl_xor(st, 2);
            st += __shfl_xor(st, 4); st += __shfl_xor(st, 8);
            if (l15 == 0) {
                dscp[(size_t)row * 8 + slot] = sd;
                tscp[(size_t)row * 8 + slot] = st;
            }
        }
    }
}

// ---------------- GRU scan (r13: MFMA engine, M=1, 64 blocks) -------------
// r12 post-mortem: 4 blocks -> gi stream concentrated on 4 CUs (62 GB/s,
// 0.38% occupancy) = BW/latency wall. Here: 64 blocks (dir*32+b), each owns
// ONE sequence as M-row 0 of the 16-row MFMA tile (rows 1-15 pad; C rows are
// independent in M so pad garbage never escapes). gi per CU = r6 levels.
// All lanes broadcast-read the single h row from 1KB LDS (conflict-free);
// wave w covers gate cols j=w*16+l15 via tiles {w, w+8, w+16}; owner lanes
// (l4==0) get r/z/n in accX[0] directly -> no shfl, one barrier/step.
// 3-pass split-bf16 = fp32-accurate recurrence. Whh persistent in VGPRs.
__global__ __launch_bounds__(512, 1) void gru_scan_mfma_kernel(
    const float* __restrict__ gi,
    const unsigned short* __restrict__ WhhH, const unsigned short* __restrict__ WhhL,
    const float* __restrict__ bhh_f, const float* __restrict__ bhh_b,
    float* __restrict__ sent_rep, unsigned short* __restrict__ srh,
    float* __restrict__ hT)
{
    const int blk = blockIdx.x;
    const int dir = blk >> 5;
    const int b   = blk & 31;
    const int t = threadIdx.x;
    const int lane = t & 63;
    const int w = t >> 6;              // wave 0..7
    const int l15 = lane & 15, l4 = lane >> 4;
    const int j = w * 16 + l15;        // gate/hidden col 0..127
    const bool owner = (l4 == 0);
    const float* bhh = dir ? bhh_b : bhh_f;
    __shared__ unsigned short hls[2][2][128];   // [buf][hi/lo][col]

    // persistent B fragments: gate g -> Whh rows g*128 + j, k = kt*32 + l4*8
    const unsigned short* WH = WhhH + (size_t)dir * 49152;
    const unsigned short* WL = WhhL + (size_t)dir * 49152;
    short8v bh0[4], bh1[4], bh2[4], bl0[4], bl1[4], bl2[4];
    #pragma unroll
    for (int kt = 0; kt < 4; ++kt) {
        const size_t ko = (size_t)kt * 32 + l4 * 8;
        bh0[kt] = *reinterpret_cast<const short8v*>(WH + (size_t)(0 * 128 + j) * 128 + ko);
        bh1[kt] = *reinterpret_cast<const short8v*>(WH + (size_t)(1 * 128 + j) * 128 + ko);
        bh2[kt] = *reinterpret_cast<const short8v*>(WH + (size_t)(2 * 128 + j) * 128 + ko);
        bl0[kt] = *reinterpret_cast<const short8v*>(WL + (size_t)(0 * 128 + j) * 128 + ko);
        bl1[kt] = *reinterpret_cast<const short8v*>(WL + (size_t)(1 * 128 + j) * 128 + ko);
        bl2[kt] = *reinterpret_cast<const short8v*>(WL + (size_t)(2 * 128 + j) * 128 + ko);
    }
    const float b_r = bhh[j], b_z = bhh[128 + j], b_n = bhh[256 + j];

    if (t < 2 * 2 * 128) ((unsigned short*)hls)[t] = 0;

    // gi prefetch (parity, depth-2): a* even steps, b* odd; unclamped +-2
    // over/under-run lands in adjacent live ws regions (never consumed).
    const float* gbase = gi + (size_t)(b * Sk) * GI_N + dir * 384 + j;
    float ar = 0.f, az = 0.f, an_ = 0.f, brr = 0.f, bzz = 0.f, bnn = 0.f;
    if (owner) {
        const long s0 = dir ? (Sk - 1) : 0;
        const long s1 = dir ? (Sk - 2) : 1;
        const float* g0 = gbase + s0 * GI_N;
        ar = g0[0]; az = g0[128]; an_ = g0[256];
        const float* g1 = gbase + s1 * GI_N;
        brr = g1[0]; bzz = g1[128]; bnn = g1[256];
    }
    float hprev = 0.f;
    __syncthreads();

    int cur = 0;
    #define SSTEP(GR, GZ, GN, SEXPR) { \
        const int s = (SEXPR); \
        short8v ah[4], al[4]; \
        _Pragma("unroll") \
        for (int kt = 0; kt < 4; ++kt) { \
            ah[kt] = *reinterpret_cast<const short8v*>(&hls[cur][0][kt*32 + l4*8]); \
            al[kt] = *reinterpret_cast<const short8v*>(&hls[cur][1][kt*32 + l4*8]); \
        } \
        f32x4 accR = {}, accZ = {}, accN = {}; \
        _Pragma("unroll") \
        for (int kt = 0; kt < 4; ++kt) { \
            accR = __builtin_amdgcn_mfma_f32_16x16x32_bf16(ah[kt], bh0[kt], accR, 0, 0, 0); \
            accR = __builtin_amdgcn_mfma_f32_16x16x32_bf16(al[kt], bh0[kt], accR, 0, 0, 0); \
            accR = __builtin_amdgcn_mfma_f32_16x16x32_bf16(ah[kt], bl0[kt], accR, 0, 0, 0); \
            accZ = __builtin_amdgcn_mfma_f32_16x16x32_bf16(ah[kt], bh1[kt], accZ, 0, 0, 0); \
            accZ = __builtin_amdgcn_mfma_f32_16x16x32_bf16(al[kt], bh1[kt], accZ, 0, 0, 0); \
            accZ = __builtin_amdgcn_mfma_f32_16x16x32_bf16(ah[kt], bl1[kt], accZ, 0, 0, 0); \
            accN = __builtin_amdgcn_mfma_f32_16x16x32_bf16(ah[kt], bh2[kt], accN, 0, 0, 0); \
            accN = __builtin_amdgcn_mfma_f32_16x16x32_bf16(al[kt], bh2[kt], accN, 0, 0, 0); \
            accN = __builtin_amdgcn_mfma_f32_16x16x32_bf16(ah[kt], bl2[kt], accN, 0, 0, 0); \
        } \
        const int nxt = cur ^ 1; \
        if (owner) { \
            float rr = fast_sigmoid(GR + accR[0] + b_r); \
            float zz = fast_sigmoid(GZ + accZ[0] + b_z); \
            float nn = fast_tanh(GN + rr * (accN[0] + b_n)); \
            float hnew = (1.f - zz) * nn + zz * hprev; \
            hprev = hnew; \
            const size_t orow = ((size_t)(b * Sk + s)) * 256 + dir * 128 + j; \
            sent_rep[orow] = hnew; \
            srh[orow] = f2bf(hnew); \
            unsigned short hh = f2bf(hnew); \
            hls[nxt][0][j] = hh; \
            hls[nxt][1][j] = f2bf(hnew - bf2f(hh)); \
            const long sn = dir ? (long)s - 2 : (long)s + 2; \
            const float* gp = gbase + sn * GI_N; \
            GR = gp[0]; GZ = gp[128]; GN = gp[256]; \
        } \
        barrier_lgkm(); \
        cur ^= 1; \
    }

    for (int step = 0; step < Sk; step += 2) {
        SSTEP(ar, az, an_, dir ? (Sk - 1 - step) : step);
        SSTEP(brr, bzz, bnn, dir ? (Sk - 2 - step) : (step + 1));
    }
    #undef SSTEP

    if (owner) hT[dir * 4096 + b * 128 + j] = hprev;
}

// ---------------- prep: doc_vec + topic_mat + tidmap (fused) --------------
__device__ __forceinline__ float4 sr_load_guard(const float* sr, int b, int sidx, int j4) {
    if (sidx < 0 || sidx >= Sk) { float4 z = {0,0,0,0}; return z; }
    return reinterpret_cast<const float4*>(sr)[(size_t)(b * Sk + sidx) * 64 + j4];
}
__global__ __launch_bounds__(64) void prep_kernel(
    const int* __restrict__ tse, const float* __restrict__ sent_rep,
    const float* __restrict__ hT, float* __restrict__ dvtm,
    unsigned short* __restrict__ dvtmH, unsigned short* __restrict__ dvtmL,
    int* __restrict__ tidmap)
{
    const int b = blockIdx.x;
    const int t = blockIdx.y;
    const int j4 = threadIdx.x;
    float4 v;
    int row;
    if (t == 16) {
        int dir = b >> 4;
        int bb = 2 * (b & 15) + (j4 >> 5);
        int jj4 = j4 & 31;
        v = reinterpret_cast<const float4*>(hT)[dir * 1024 + bb * 32 + jj4];
        row = b;
        for (int ss = j4; ss < 256; ss += 64) {
            int ti = 0;
            #pragma unroll
            for (int tt = 1; tt < 16; ++tt) ti += (ss >= tse[b * 32 + tt * 2] - 1) ? 1 : 0;
            tidmap[b * 256 + ss] = ti;
        }
    } else {
        int st = tse[b * 32 + t * 2];
        int en = tse[b * 32 + t * 2 + 1];
        float4 va, vb;
        if (j4 < 32) {
            va = sr_load_guard(sent_rep, b, en - 1, j4);
            vb = sr_load_guard(sent_rep, b, st - 2, j4);
        } else {
            va = sr_load_guard(sent_rep, b, st - 1, j4);
            vb = sr_load_guard(sent_rep, b, en, j4);
        }
        v.x = va.x - vb.x; v.y = va.y - vb.y; v.z = va.z - vb.z; v.w = va.w - vb.w;
        row = 32 + b * 16 + t;
    }
    reinterpret_cast<float4*>(dvtm)[row * 64 + j4] = v;
    ushort4 h, l;
    h.x = f2bf(v.x); h.y = f2bf(v.y); h.z = f2bf(v.z); h.w = f2bf(v.w);
    l.x = f2bf(v.x - bf2f(h.x)); l.y = f2bf(v.y - bf2f(h.y));
    l.z = f2bf(v.z - bf2f(h.z)); l.w = f2bf(v.w - bf2f(h.w));
    *reinterpret_cast<ushort4*>(dvtmH + (size_t)row * 256 + j4 * 4) = h;
    *reinterpret_cast<ushort4*>(dvtmL + (size_t)row * 256 + j4 * 4) = l;
}

// ---------------- softmax (sums partials, outputs weights) ----------------
__global__ __launch_bounds__(256) void softmax_kernel(
    const float* __restrict__ dscp, const float* __restrict__ tscp,
    float* __restrict__ dsc, float* __restrict__ tsc)
{
    const int b = blockIdx.x, sidx = threadIdx.x;
    const int lane = sidx & 63, wid = sidx >> 6;
    __shared__ float rd[4], rt[4];
    const float4* dp8 = reinterpret_cast<const float4*>(dscp + (size_t)(b * Sk + sidx) * 8);
    const float4* tp8 = reinterpret_cast<const float4*>(tscp + (size_t)(b * Sk + sidx) * 8);
    float4 d0 = dp8[0], d1 = dp8[1], t0 = tp8[0], t1 = tp8[1];
    float d = ((d0.x + d0.y) + (d0.z + d0.w)) + ((d1.x + d1.y) + (d1.z + d1.w));
    float t = ((t0.x + t0.y) + (t0.z + t0.w)) + ((t1.x + t1.y) + (t1.z + t1.w));
    float md = d, mt = t;
    #pragma unroll
    for (int off = 32; off; off >>= 1) {
        md = fmaxf(md, __shfl_xor(md, off));
        mt = fmaxf(mt, __shfl_xor(mt, off));
    }
    if (lane == 0) { rd[wid] = md; rt[wid] = mt; }
    __syncthreads();
    md = fmaxf(fmaxf(rd[0], rd[1]), fmaxf(rd[2], rd[3]));
    mt = fmaxf(fmaxf(rt[0], rt[1]), fmaxf(rt[2], rt[3]));
    float ed = __expf(d - md), et = __expf(t - mt);
    float sd = ed, stt = et;
    #pragma unroll
    for (int off = 32; off; off >>= 1) {
        sd += __shfl_xor(sd, off);
        stt += __shfl_xor(stt, off);
    }
    __syncthreads();
    if (lane == 0) { rd[wid] = sd; rt[wid] = stt; }
    __syncthreads();
    sd = rd[0] + rd[1] + rd[2] + rd[3];
    stt = rt[0] + rt[1] + rt[2] + rt[3];
    dsc[b * Sk + sidx] = ed / sd;
    tsc[b * Sk + sidx] = et / stt;
}

// ---------------- build inp (bf16 hi/lo) = [sent_rep, context] ------------
__global__ __launch_bounds__(128) void build_inp_kernel(
    const float* __restrict__ sent_rep, const float* __restrict__ dvtm,
    const float* __restrict__ dw, const float* __restrict__ tw,
    const int* __restrict__ tidmap,
    unsigned short* __restrict__ inpH, unsigned short* __restrict__ inpL)
{
    int row = blockIdx.x;
    int b = row >> 8;
    int f4c = threadIdx.x;
    float4 v;
    if (f4c < 64) {
        v = reinterpret_cast<const float4*>(sent_rep)[(size_t)row * 64 + f4c];
    } else {
        int ti = tidmap[row];
        float dwv = dw[row], twv = tw[row];
        int j4 = f4c - 64;
        float4 dv = reinterpret_cast<const float4*>(dvtm)[b * 64 + j4];
        float4 tm = reinterpret_cast<const float4*>(dvtm)[(32 + b * 16 + ti) * 64 + j4];
        v.x = dwv * dv.x + twv * tm.x;
        v.y = dwv * dv.y + twv * tm.y;
        v.z = dwv * dv.z + twv * tm.z;
        v.w = dwv * dv.w + twv * tm.w;
    }
    ushort4 h, l;
    h.x = f2bf(v.x); h.y = f2bf(v.y); h.z = f2bf(v.z); h.w = f2bf(v.w);
    l.x = f2bf(v.x - bf2f(h.x)); l.y = f2bf(v.y - bf2f(h.y));
    l.z = f2bf(v.z - bf2f(h.z)); l.w = f2bf(v.w - bf2f(h.w));
    *reinterpret_cast<ushort4*>(inpH + (size_t)row * 512 + f4c * 4) = h;
    *reinterpret_cast<ushort4*>(inpL + (size_t)row * 512 + f4c * 4) = l;
}

// ---------------- launch ----------------
extern "C" void kernel_launch(void* const* d_in, const int* in_sizes, int n_in,
                              void* d_out, int out_size, void* d_ws, size_t ws_size,
                              hipStream_t stream)
{
    const int*   wids  = (const int*)d_in[0];
    const int*   tse   = (const int*)d_in[1];
    const float* table = (const float*)d_in[2];
    const float* Wihf  = (const float*)d_in[3];
    const float* Whhf  = (const float*)d_in[4];
    const float* bihf  = (const float*)d_in[5];
    const float* bhhf  = (const float*)d_in[6];
    const float* Wihb  = (const float*)d_in[7];
    const float* Whhb  = (const float*)d_in[8];
    const float* bihb  = (const float*)d_in[9];
    const float* bhhb  = (const float*)d_in[10];
    const float* vatt  = (const float*)d_in[11];
    const float* Watt  = (const float*)d_in[12];
    const float* W1    = (const float*)d_in[13];
    const float* b1    = (const float*)d_in[14];
    const float* W2    = (const float*)d_in[15];
    const float* b2    = (const float*)d_in[16];
    float* ws = (float*)d_ws;
    float* out = (float*)d_out;

    // layout (float units)
    unsigned short* Ahi   = (unsigned short*)(ws + 0);          // 1,310,720 f
    unsigned short* Alo   = (unsigned short*)(ws + 1310720);    // 1,310,720 f
    float* gi             = ws + 2621440;                       // 6,291,456
    float* sent_rep       = ws + 8912896;                       // 2,097,152
    unsigned short* SRhi  = (unsigned short*)(ws + 11010048);   // 1,048,576 f
    float* hT             = ws + 12058624;                      // 8,192
    float* dvtm           = ws + 12066816;                      // 139,264
    float* dptp           = ws + 12206080;                      // 327,680 (640x512)
    float* dsc            = ws + 12533760;                      // 8,192
    float* tsc            = ws + 12541952;                      // 8,192
    unsigned short* BgtH  = (unsigned short*)(ws + 12550144);   // 122,880 f
    unsigned short* BgtL  = (unsigned short*)(ws + 12673024);   // 122,880 f
    float* bias_gi        = ws + 12795904;                      // 768
    unsigned short* Wswt  = (unsigned short*)(ws + 12796672);   // 65,536 f
    unsigned short* W1H   = (unsigned short*)(ws + 12862208);   // 32,768 f
    unsigned short* W1L   = (unsigned short*)(ws + 12894976);   // 32,768 f
    float* dscp           = ws + 12927744;                      // 65,536
    float* tscp           = ws + 12993280;                      // 65,536
    int*   tidmap         = (int*)(ws + 13058816);              // 8,192
    unsigned short* dvtmH = (unsigned short*)(ws + 13067008);   // 81,920 f
    unsigned short* dvtmL = (unsigned short*)(ws + 13148928);   // 81,920 f
    unsigned short* WatTH = (unsigned short*)(ws + 13230848);   // 65,536 f
    unsigned short* WatTL = (unsigned short*)(ws + 13296384);   // 65,536 f
    unsigned short* WhhHp = (unsigned short*)(ws + 13361920);   // 49,152 f
    unsigned short* WhhLp = (unsigned short*)(ws + 13411072);   // 49,152 f
    // end 13,460,224 floats
    // dead-zone reuse (Ahi/Alo/gi dead after scan):
    unsigned short* inpH  = (unsigned short*)(ws + 0);          // 2,097,152 f
    unsigned short* inpL  = (unsigned short*)(ws + 2097152);    // 2,097,152 f

    if (ws_size < (size_t)13460224 * sizeof(float)) return;

    pack_kernel<<<960, 256, 0, stream>>>(Wihf, Wihb, Whhf, Whhb, bihf, bihb,
                                         Watt, W1, BgtH, BgtL, bias_gi, Wswt,
                                         W1H, W1L, WatTH, WatTL, WhhHp, WhhLp);
    embed_mean_kernel<<<2048, 256, 0, stream>>>(wids, table, Ahi, Alo);
    mfma_gemm_kernel<3, true, false><<<dim3(64, 6), 256, 0, stream>>>(
        Ahi, Alo, BgtH, BgtL, bias_gi, gi, NROWS, 768, KPAD);
    gru_scan_mfma_kernel<<<64, 512, 0, stream>>>(gi, WhhHp, WhhLp, bhhf, bhhb,
                                                 sent_rep, SRhi, hT);
    prep_kernel<<<dim3(32, 17), 64, 0, stream>>>(tse, sent_rep, hT, dvtm,
                                                 dvtmH, dvtmL, tidmap);
    mfma_gemm_kernel<3, false, false><<<dim3(5, 4), 256, 0, stream>>>(
        dvtmH, dvtmL, WatTH, WatTL, nullptr, dptp, 640, 512, 256);
    mfma_swscore_kernel<<<dim3(64, 4), 256, 0, stream>>>(
        SRhi, Wswt, dptp, vatt, tidmap, dscp, tscp);
    softmax_kernel<<<32, 256, 0, stream>>>(dscp, tscp, dsc, tsc);
    build_inp_kernel<<<NROWS, 128, 0, stream>>>(sent_rep, dvtm, dsc, tsc, tidmap, inpH, inpL);
    mfma_w1_logits_kernel<<<dim3(64, 1), 256, 0, stream>>>(
        inpH, inpL, W1H, W1L, b1, W2, b2, out);
}

// Round 14
// 331.417 us; speedup vs baseline: 1.7007x; 1.1150x over previous
//
#include <hip/hip_runtime.h>
#include <hip/hip_bf16.h>
#include <cstdint>

// Problem constants
#define Bk 32
#define Sk 256
#define Wk 32
#define Tk 16
#define Ek 300
#define Hk 128
#define Dk 128
#define NROWS (Bk*Sk)          // 8192
#define GI_N  (3*Hk*2)         // 768
#define KPAD  320              // 300 padded to multiple of 32

typedef __attribute__((ext_vector_type(8))) short short8v;
typedef __attribute__((ext_vector_type(4))) float f32x4;

// ---------------- helpers ----------------
__device__ __forceinline__ float fast_sigmoid(float x) {
    return 1.f / (1.f + __expf(-x));
}
__device__ __forceinline__ float fast_tanh(float x) {
    float ax = fabsf(x);
    float e = __expf(2.f * ax);
    float t = 1.f - 2.f / (1.f + e);
    return copysignf(t, x);
}
__device__ __forceinline__ void barrier_lgkm() {
    asm volatile("s_waitcnt lgkmcnt(0)" ::: "memory");
    __builtin_amdgcn_s_barrier();
}
// fp32 -> bf16 (RNE), finite inputs
__device__ __forceinline__ unsigned short f2bf(float f) {
    uint32_t u = __float_as_uint(f);
    uint32_t r = (u + 0x7FFFu + ((u >> 16) & 1u)) >> 16;
    return (unsigned short)r;
}
__device__ __forceinline__ float bf2f(unsigned short h) {
    return __uint_as_float(((uint32_t)h) << 16);
}

// ---------------- pack kernel ----------------
__global__ __launch_bounds__(256) void pack_kernel(
    const float* __restrict__ Wf, const float* __restrict__ Wb,
    const float* __restrict__ bf, const float* __restrict__ bb,
    const float* __restrict__ Watt, const float* __restrict__ W1,
    unsigned short* __restrict__ Bgt_hi, unsigned short* __restrict__ Bgt_lo,
    float* __restrict__ bias_gi, unsigned short* __restrict__ Wswt,
    unsigned short* __restrict__ W1H, unsigned short* __restrict__ W1L,
    unsigned short* __restrict__ WatTopH, unsigned short* __restrict__ WatTopL)
{
    int idx = blockIdx.x * 256 + threadIdx.x;
    if (idx < 768 * KPAD) {
        int n = idx / KPAD, k = idx % KPAD;
        float v = 0.f;
        if (k < 300) v = (n < 384) ? Wf[n * 300 + k] : Wb[(n - 384) * 300 + k];
        unsigned short h = f2bf(v);
        Bgt_hi[idx] = h;
        Bgt_lo[idx] = f2bf(v - bf2f(h));
    }
    if (idx < 768) bias_gi[idx] = (idx < 384) ? bf[idx] : bb[idx - 384];
    if (idx < 512 * 256) {
        int n = idx >> 8, k = idx & 255;
        // Wswt: Watt rows 256..511 transposed (sent part)
        Wswt[idx] = f2bf(Watt[(size_t)(256 + k) * 512 + n]);
        // WatTop: Watt rows 0..255 transposed (doc/topic part), split hi/lo
        float v = Watt[(size_t)k * 512 + n];
        unsigned short h = f2bf(v);
        WatTopH[idx] = h;
        WatTopL[idx] = f2bf(v - bf2f(h));
    }
    if (idx < 128 * 512) {
        float v = W1[idx];
        unsigned short h = f2bf(v);
        W1H[idx] = h;
        W1L[idx] = f2bf(v - bf2f(h));
    }
}

// ---------------- embedding mean -> bf16 hi/lo [8192][320] ----------------
__global__ __launch_bounds__(256) void embed_mean_kernel(
    const int* __restrict__ wids, const float* __restrict__ table,
    unsigned short* __restrict__ Ahi, unsigned short* __restrict__ Alo)
{
    int wv = (blockIdx.x << 2) + (threadIdx.x >> 6);
    int lane = threadIdx.x & 63;
    if (wv >= NROWS) return;
    const int* idp = wids + (size_t)wv * Wk;
    float4 a0 = {0,0,0,0}, a1 = {0,0,0,0};
    #pragma unroll 4
    for (int w = 0; w < Wk; ++w) {
        int id = idp[w];
        const float4* r4 = reinterpret_cast<const float4*>(table + (size_t)id * Ek);
        float4 v0 = r4[lane];
        a0.x += v0.x; a0.y += v0.y; a0.z += v0.z; a0.w += v0.w;
        if (lane < 11) {
            float4 v1 = r4[64 + lane];
            a1.x += v1.x; a1.y += v1.y; a1.z += v1.z; a1.w += v1.w;
        }
    }
    const float sc = 1.f / 32.f;
    unsigned short* hp = Ahi + (size_t)wv * KPAD;
    unsigned short* lp = Alo + (size_t)wv * KPAD;
    {
        float v[4] = {a0.x*sc, a0.y*sc, a0.z*sc, a0.w*sc};
        ushort4 h, l;
        h.x=f2bf(v[0]); h.y=f2bf(v[1]); h.z=f2bf(v[2]); h.w=f2bf(v[3]);
        l.x=f2bf(v[0]-bf2f(h.x)); l.y=f2bf(v[1]-bf2f(h.y));
        l.z=f2bf(v[2]-bf2f(h.z)); l.w=f2bf(v[3]-bf2f(h.w));
        *reinterpret_cast<ushort4*>(hp + lane*4) = h;
        *reinterpret_cast<ushort4*>(lp + lane*4) = l;
    }
    if (lane < 11) {
        float v[4] = {a1.x*sc, a1.y*sc, a1.z*sc, a1.w*sc};
        ushort4 h, l;
        h.x=f2bf(v[0]); h.y=f2bf(v[1]); h.z=f2bf(v[2]); h.w=f2bf(v[3]);
        l.x=f2bf(v[0]-bf2f(h.x)); l.y=f2bf(v[1]-bf2f(h.y));
        l.z=f2bf(v[2]-bf2f(h.z)); l.w=f2bf(v[3]-bf2f(h.w));
        *reinterpret_cast<ushort4*>(hp + 256 + lane*4) = h;
        *reinterpret_cast<ushort4*>(lp + 256 + lane*4) = l;
    } else if (lane < 16) {
        ushort4 z = {0,0,0,0};
        *reinterpret_cast<ushort4*>(hp + 256 + lane*4) = z;
        *reinterpret_cast<ushort4*>(lp + 256 + lane*4) = z;
    }
}

// ---------------- MFMA bf16 GEMM: C[M,N] = A @ Bt^T (+bias, relu) ---------
template<int PASSES, bool BIAS, bool RELU>
__global__ __launch_bounds__(256) void mfma_gemm_kernel(
    const unsigned short* __restrict__ Ahi, const unsigned short* __restrict__ Alo,
    const unsigned short* __restrict__ Bthi, const unsigned short* __restrict__ Btlo,
    const float* __restrict__ bias, float* __restrict__ C,
    int M, int N, int Kp)
{
    __shared__ unsigned short At_h[128][40];
    __shared__ unsigned short Bt_h[128][40];
    __shared__ unsigned short At_l[128][40];
    __shared__ unsigned short Bt_l[128][40];
    const int tid = threadIdx.x;
    const int m0 = blockIdx.x * 128, n0 = blockIdx.y * 128;
    const int lane = tid & 63;
    const int wave = tid >> 6;
    const int wr = (wave >> 1) * 64, wc = (wave & 1) * 64;
    const int l15 = lane & 15, l4 = lane >> 4;
    f32x4 acc[4][4] = {};

    const int srow = tid >> 1;
    const int scol = (tid & 1) * 16;

    for (int k0 = 0; k0 < Kp; k0 += 32) {
        {
            const unsigned short* ag = Ahi + (size_t)(m0 + srow) * Kp + k0 + scol;
            *reinterpret_cast<short8v*>(&At_h[srow][scol])     = *reinterpret_cast<const short8v*>(ag);
            *reinterpret_cast<short8v*>(&At_h[srow][scol + 8]) = *reinterpret_cast<const short8v*>(ag + 8);
            const unsigned short* bg = Bthi + (size_t)(n0 + srow) * Kp + k0 + scol;
            *reinterpret_cast<short8v*>(&Bt_h[srow][scol])     = *reinterpret_cast<const short8v*>(bg);
            *reinterpret_cast<short8v*>(&Bt_h[srow][scol + 8]) = *reinterpret_cast<const short8v*>(bg + 8);
            if (PASSES > 1) {
                const unsigned short* ag2 = Alo + (size_t)(m0 + srow) * Kp + k0 + scol;
                *reinterpret_cast<short8v*>(&At_l[srow][scol])     = *reinterpret_cast<const short8v*>(ag2);
                *reinterpret_cast<short8v*>(&At_l[srow][scol + 8]) = *reinterpret_cast<const short8v*>(ag2 + 8);
                const unsigned short* bg2 = Btlo + (size_t)(n0 + srow) * Kp + k0 + scol;
                *reinterpret_cast<short8v*>(&Bt_l[srow][scol])     = *reinterpret_cast<const short8v*>(bg2);
                *reinterpret_cast<short8v*>(&Bt_l[srow][scol + 8]) = *reinterpret_cast<const short8v*>(bg2 + 8);
            }
        }
        __syncthreads();
        short8v a_h[4], b_h[4], a_l[4], b_l[4];
        #pragma unroll
        for (int f = 0; f < 4; ++f) {
            a_h[f] = *reinterpret_cast<const short8v*>(&At_h[wr + f*16 + l15][l4*8]);
            b_h[f] = *reinterpret_cast<const short8v*>(&Bt_h[wc + f*16 + l15][l4*8]);
            if (PASSES > 1) {
                a_l[f] = *reinterpret_cast<const short8v*>(&At_l[wr + f*16 + l15][l4*8]);
                b_l[f] = *reinterpret_cast<const short8v*>(&Bt_l[wc + f*16 + l15][l4*8]);
            }
        }
        #pragma unroll
        for (int i = 0; i < 4; ++i) {
            #pragma unroll
            for (int j = 0; j < 4; ++j) {
                acc[i][j] = __builtin_amdgcn_mfma_f32_16x16x32_bf16(a_h[i], b_h[j], acc[i][j], 0, 0, 0);
                if (PASSES > 1) {
                    acc[i][j] = __builtin_amdgcn_mfma_f32_16x16x32_bf16(a_l[i], b_h[j], acc[i][j], 0, 0, 0);
                    acc[i][j] = __builtin_amdgcn_mfma_f32_16x16x32_bf16(a_h[i], b_l[j], acc[i][j], 0, 0, 0);
                }
            }
        }
        __syncthreads();
    }
    #pragma unroll
    for (int i = 0; i < 4; ++i) {
        #pragma unroll
        for (int j = 0; j < 4; ++j) {
            int col = n0 + wc + j * 16 + l15;
            float badd = BIAS ? bias[col] : 0.f;
            #pragma unroll
            for (int r = 0; r < 4; ++r) {
                int row = m0 + wr + i * 16 + l4 * 4 + r;
                float v = acc[i][j][r] + badd;
                if (RELU) v = fmaxf(v, 0.f);
                C[(size_t)row * N + col] = v;
            }
        }
    }
}

// ---------------- MFMA W1 GEMM with fused logits ---------------------------
// hdd = relu(inp @ W1^T + b1) computed in-register; logits[row] =
// sum_col hdd*W2[col] + b2 reduced via 16-lane shfl + cross-wave LDS.
// N=128 (one block covers all cols), Kp=512, grid (64,1). No hdd store.
__global__ __launch_bounds__(256) void mfma_w1_logits_kernel(
    const unsigned short* __restrict__ Ahi, const unsigned short* __restrict__ Alo,
    const unsigned short* __restrict__ Bthi, const unsigned short* __restrict__ Btlo,
    const float* __restrict__ b1, const float* __restrict__ W2,
    const float* __restrict__ b2, float* __restrict__ out)
{
    __shared__ unsigned short At_h[128][40];
    __shared__ unsigned short Bt_h[128][40];
    __shared__ unsigned short At_l[128][40];
    __shared__ unsigned short Bt_l[128][40];
    __shared__ float lpart[128];
    const int Kp = 512;
    const int tid = threadIdx.x;
    const int m0 = blockIdx.x * 128;
    const int lane = tid & 63;
    const int wave = tid >> 6;
    const int wr = (wave >> 1) * 64, wc = (wave & 1) * 64;
    const int l15 = lane & 15, l4 = lane >> 4;
    f32x4 acc[4][4] = {};

    const int srow = tid >> 1;
    const int scol = (tid & 1) * 16;

    for (int k0 = 0; k0 < Kp; k0 += 32) {
        {
            const unsigned short* ag = Ahi + (size_t)(m0 + srow) * Kp + k0 + scol;
            *reinterpret_cast<short8v*>(&At_h[srow][scol])     = *reinterpret_cast<const short8v*>(ag);
            *reinterpret_cast<short8v*>(&At_h[srow][scol + 8]) = *reinterpret_cast<const short8v*>(ag + 8);
            const unsigned short* bg = Bthi + (size_t)srow * Kp + k0 + scol;
            *reinterpret_cast<short8v*>(&Bt_h[srow][scol])     = *reinterpret_cast<const short8v*>(bg);
            *reinterpret_cast<short8v*>(&Bt_h[srow][scol + 8]) = *reinterpret_cast<const short8v*>(bg + 8);
            const unsigned short* ag2 = Alo + (size_t)(m0 + srow) * Kp + k0 + scol;
            *reinterpret_cast<short8v*>(&At_l[srow][scol])     = *reinterpret_cast<const short8v*>(ag2);
            *reinterpret_cast<short8v*>(&At_l[srow][scol + 8]) = *reinterpret_cast<const short8v*>(ag2 + 8);
            const unsigned short* bg2 = Btlo + (size_t)srow * Kp + k0 + scol;
            *reinterpret_cast<short8v*>(&Bt_l[srow][scol])     = *reinterpret_cast<const short8v*>(bg2);
            *reinterpret_cast<short8v*>(&Bt_l[srow][scol + 8]) = *reinterpret_cast<const short8v*>(bg2 + 8);
        }
        __syncthreads();
        short8v a_h[4], b_h[4], a_l[4], b_l[4];
        #pragma unroll
        for (int f = 0; f < 4; ++f) {
            a_h[f] = *reinterpret_cast<const short8v*>(&At_h[wr + f*16 + l15][l4*8]);
            b_h[f] = *reinterpret_cast<const short8v*>(&Bt_h[wc + f*16 + l15][l4*8]);
            a_l[f] = *reinterpret_cast<const short8v*>(&At_l[wr + f*16 + l15][l4*8]);
            b_l[f] = *reinterpret_cast<const short8v*>(&Bt_l[wc + f*16 + l15][l4*8]);
        }
        #pragma unroll
        for (int i = 0; i < 4; ++i) {
            #pragma unroll
            for (int j = 0; j < 4; ++j) {
                acc[i][j] = __builtin_amdgcn_mfma_f32_16x16x32_bf16(a_h[i], b_h[j], acc[i][j], 0, 0, 0);
                acc[i][j] = __builtin_amdgcn_mfma_f32_16x16x32_bf16(a_l[i], b_h[j], acc[i][j], 0, 0, 0);
                acc[i][j] = __builtin_amdgcn_mfma_f32_16x16x32_bf16(a_h[i], b_l[j], acc[i][j], 0, 0, 0);
            }
        }
        __syncthreads();
    }
    // fused logits epilogue
    float b1v[4], w2v[4];
    #pragma unroll
    for (int j = 0; j < 4; ++j) {
        int col = wc + j * 16 + l15;
        b1v[j] = b1[col];
        w2v[j] = W2[col];
    }
    float lsum[4][4];
    #pragma unroll
    for (int i = 0; i < 4; ++i) {
        #pragma unroll
        for (int r = 0; r < 4; ++r) {
            float s = 0.f;
            #pragma unroll
            for (int j = 0; j < 4; ++j) {
                float v = fmaxf(acc[i][j][r] + b1v[j], 0.f);
                s = fmaf(v, w2v[j], s);
            }
            s += __shfl_xor(s, 1); s += __shfl_xor(s, 2);
            s += __shfl_xor(s, 4); s += __shfl_xor(s, 8);
            lsum[i][r] = s;
        }
    }
    if (wc == 0 && l15 == 0) {
        #pragma unroll
        for (int i = 0; i < 4; ++i)
            #pragma unroll
            for (int r = 0; r < 4; ++r)
                lpart[wr + i * 16 + l4 * 4 + r] = lsum[i][r];
    }
    __syncthreads();
    if (wc == 64 && l15 == 0) {
        float bb2 = b2[0];
        #pragma unroll
        for (int i = 0; i < 4; ++i)
            #pragma unroll
            for (int r = 0; r < 4; ++r) {
                int rl = wr + i * 16 + l4 * 4 + r;
                out[m0 + rl] = lpart[rl] + lsum[i][r] + bb2;
            }
    }
}

// ---------------- MFMA SW GEMM with fused attention scores ----------------
__global__ __launch_bounds__(256) void mfma_swscore_kernel(
    const unsigned short* __restrict__ Ahi, const unsigned short* __restrict__ Bthi,
    const float* __restrict__ dptp, const float* __restrict__ vatt,
    const int* __restrict__ tidmap,
    float* __restrict__ dscp, float* __restrict__ tscp)
{
    __shared__ unsigned short At_h[128][40];
    __shared__ unsigned short Bt_h[128][40];
    const int tid = threadIdx.x;
    const int m0 = blockIdx.x * 128, n0 = blockIdx.y * 128;
    const int Kp = 256;
    const int lane = tid & 63;
    const int wave = tid >> 6;
    const int wr = (wave >> 1) * 64, wc = (wave & 1) * 64;
    const int l15 = lane & 15, l4 = lane >> 4;
    f32x4 acc[4][4] = {};

    const int srow = tid >> 1;
    const int scol = (tid & 1) * 16;

    for (int k0 = 0; k0 < Kp; k0 += 32) {
        {
            const unsigned short* ag = Ahi + (size_t)(m0 + srow) * Kp + k0 + scol;
            *reinterpret_cast<short8v*>(&At_h[srow][scol])     = *reinterpret_cast<const short8v*>(ag);
            *reinterpret_cast<short8v*>(&At_h[srow][scol + 8]) = *reinterpret_cast<const short8v*>(ag + 8);
            const unsigned short* bg = Bthi + (size_t)(n0 + srow) * Kp + k0 + scol;
            *reinterpret_cast<short8v*>(&Bt_h[srow][scol])     = *reinterpret_cast<const short8v*>(bg);
            *reinterpret_cast<short8v*>(&Bt_h[srow][scol + 8]) = *reinterpret_cast<const short8v*>(bg + 8);
        }
        __syncthreads();
        short8v a_h[4], b_h[4];
        #pragma unroll
        for (int f = 0; f < 4; ++f) {
            a_h[f] = *reinterpret_cast<const short8v*>(&At_h[wr + f*16 + l15][l4*8]);
            b_h[f] = *reinterpret_cast<const short8v*>(&Bt_h[wc + f*16 + l15][l4*8]);
        }
        #pragma unroll
        for (int i = 0; i < 4; ++i)
            #pragma unroll
            for (int j = 0; j < 4; ++j)
                acc[i][j] = __builtin_amdgcn_mfma_f32_16x16x32_bf16(a_h[i], b_h[j], acc[i][j], 0, 0, 0);
        __syncthreads();
    }
    const int bb = m0 >> 8;
    const float* dpr = dptp + (size_t)bb * 512;
    float vv[4], dpv[4];
    #pragma unroll
    for (int j = 0; j < 4; ++j) {
        int col = n0 + wc + j * 16 + l15;
        vv[j] = vatt[col];
        dpv[j] = dpr[col];
    }
    const int slot = blockIdx.y * 2 + (wc >> 6);
    #pragma unroll
    for (int i = 0; i < 4; ++i) {
        #pragma unroll
        for (int r = 0; r < 4; ++r) {
            int row = m0 + wr + i * 16 + l4 * 4 + r;
            int ti = tidmap[row];
            const float* tpr = dptp + (size_t)(32 + bb * 16 + ti) * 512;
            float sd = 0.f, st = 0.f;
            #pragma unroll
            for (int j = 0; j < 4; ++j) {
                int col = n0 + wc + j * 16 + l15;
                float c = acc[i][j][r];
                sd += fast_tanh(c + dpv[j]) * vv[j];
                st += fast_tanh(c + tpr[col]) * vv[j];
            }
            sd += __shfl_xor(sd, 1); sd += __shfl_xor(sd, 2);
            sd += __shfl_xor(sd, 4); sd += __shfl_xor(sd, 8);
            st += __shfl_xor(st, 1); st += __shfl_xor(st, 2);
            st += __shfl_xor(st, 4); st += __shfl_xor(st, 8);
            if (l15 == 0) {
                dscp[(size_t)row * 8 + slot] = sd;
                tscp[(size_t)row * 8 + slot] = st;
            }
        }
    }
}

// ---------------- GRU scan (r11 structure: VALU, 4-step unroll) -----------
// Best-measured scan. r6 single-barrier structure; 4-step unroll with
// batched stores; depth-2 parity gi prefetch. 7 optimization hypotheses
// (vmcnt drain, LDS throughput, prefetch slack x2, gate distribution,
// store batching, MFMA engine x2) all failed to beat this: latency-bound
// structural floor of the sequential recurrence at 64 blocks.
__global__ __launch_bounds__(512, 1) void gru_scan_kernel(
    const float* __restrict__ gi,
    const float* __restrict__ Whh_f, const float* __restrict__ Whh_b,
    const float* __restrict__ bhh_f, const float* __restrict__ bhh_b,
    float* __restrict__ sent_rep, unsigned short* __restrict__ srh,
    float* __restrict__ hT)
{
    const int blk = blockIdx.x;
    const int dir = blk >> 5;
    const int b   = blk & 31;
    const int t = threadIdx.x;
    const int lane = t & 63;
    const int w_id = t >> 6;
    const int q = lane >> 4;
    const int m = lane & 15;
    const int j = w_id * 16 + m;
    const float* Whh = dir ? Whh_b : Whh_f;
    const float* bhh = dir ? bhh_b : bhh_f;
    __shared__ float hbufA[144];
    __shared__ float hbufB[144];

    const float* wr0 = Whh + (size_t)j * 128 + 32 * q;
    const float* wr1 = wr0 + 128 * 128;
    const float* wr2 = wr0 + 256 * 128;
    float4 wA0 = *reinterpret_cast<const float4*>(wr0 +  0);
    float4 wA1 = *reinterpret_cast<const float4*>(wr0 +  4);
    float4 wA2 = *reinterpret_cast<const float4*>(wr0 +  8);
    float4 wA3 = *reinterpret_cast<const float4*>(wr0 + 12);
    float4 wA4 = *reinterpret_cast<const float4*>(wr0 + 16);
    float4 wA5 = *reinterpret_cast<const float4*>(wr0 + 20);
    float4 wA6 = *reinterpret_cast<const float4*>(wr0 + 24);
    float4 wA7 = *reinterpret_cast<const float4*>(wr0 + 28);
    float4 wB0 = *reinterpret_cast<const float4*>(wr1 +  0);
    float4 wB1 = *reinterpret_cast<const float4*>(wr1 +  4);
    float4 wB2 = *reinterpret_cast<const float4*>(wr1 +  8);
    float4 wB3 = *reinterpret_cast<const float4*>(wr1 + 12);
    float4 wB4 = *reinterpret_cast<const float4*>(wr1 + 16);
    float4 wB5 = *reinterpret_cast<const float4*>(wr1 + 20);
    float4 wB6 = *reinterpret_cast<const float4*>(wr1 + 24);
    float4 wB7 = *reinterpret_cast<const float4*>(wr1 + 28);
    float4 wC0 = *reinterpret_cast<const float4*>(wr2 +  0);
    float4 wC1 = *reinterpret_cast<const float4*>(wr2 +  4);
    float4 wC2 = *reinterpret_cast<const float4*>(wr2 +  8);
    float4 wC3 = *reinterpret_cast<const float4*>(wr2 + 12);
    float4 wC4 = *reinterpret_cast<const float4*>(wr2 + 16);
    float4 wC5 = *reinterpret_cast<const float4*>(wr2 + 20);
    float4 wC6 = *reinterpret_cast<const float4*>(wr2 + 24);
    float4 wC7 = *reinterpret_cast<const float4*>(wr2 + 28);
    const float br = bhh[j];
    const float bz = bhh[128 + j];
    const float bn = bhh[256 + j];

    if (t < 144) { hbufA[t] = 0.f; hbufB[t] = 0.f; }

    const int ji = 36 * (j >> 5) + (j & 31);
    const float* gbase = gi + (size_t)(b * Sk) * GI_N + dir * 384 + j;
    float hold = 0.f;
    float ar = 0.f, az = 0.f, an_ = 0.f;
    float brr = 0.f, bzz = 0.f, bnn = 0.f;
    {
        const long s0 = dir ? (Sk - 1) : 0;
        const long s1 = dir ? (Sk - 2) : 1;
        const float* g0 = gbase + s0 * GI_N;
        ar = g0[0]; az = g0[128]; an_ = g0[256];
        const float* g1 = gbase + s1 * GI_N;
        brr = g1[0]; bzz = g1[128]; bnn = g1[256];
    }
    __syncthreads();

    #define STEP(RD, WR, SEXPR, GR, GZ, GN, SAVE) { \
        const int s = (SEXPR); \
        const float4* hseg = reinterpret_cast<const float4*>(RD) + 9 * q; \
        float pA = 0.f, pB = 0.f, pC = 0.f; \
        { float4 h4; \
          h4 = hseg[0]; \
          pA=fmaf(wA0.x,h4.x,pA); pA=fmaf(wA0.y,h4.y,pA); pA=fmaf(wA0.z,h4.z,pA); pA=fmaf(wA0.w,h4.w,pA); \
          pB=fmaf(wB0.x,h4.x,pB); pB=fmaf(wB0.y,h4.y,pB); pB=fmaf(wB0.z,h4.z,pB); pB=fmaf(wB0.w,h4.w,pB); \
          pC=fmaf(wC0.x,h4.x,pC); pC=fmaf(wC0.y,h4.y,pC); pC=fmaf(wC0.z,h4.z,pC); pC=fmaf(wC0.w,h4.w,pC); \
          h4 = hseg[1]; \
          pA=fmaf(wA1.x,h4.x,pA); pA=fmaf(wA1.y,h4.y,pA); pA=fmaf(wA1.z,h4.z,pA); pA=fmaf(wA1.w,h4.w,pA); \
          pB=fmaf(wB1.x,h4.x,pB); pB=fmaf(wB1.y,h4.y,pB); pB=fmaf(wB1.z,h4.z,pB); pB=fmaf(wB1.w,h4.w,pB); \
          pC=fmaf(wC1.x,h4.x,pC); pC=fmaf(wC1.y,h4.y,pC); pC=fmaf(wC1.z,h4.z,pC); pC=fmaf(wC1.w,h4.w,pC); \
          h4 = hseg[2]; \
          pA=fmaf(wA2.x,h4.x,pA); pA=fmaf(wA2.y,h4.y,pA); pA=fmaf(wA2.z,h4.z,pA); pA=fmaf(wA2.w,h4.w,pA); \
          pB=fmaf(wB2.x,h4.x,pB); pB=fmaf(wB2.y,h4.y,pB); pB=fmaf(wB2.z,h4.z,pB); pB=fmaf(wB2.w,h4.w,pB); \
          pC=fmaf(wC2.x,h4.x,pC); pC=fmaf(wC2.y,h4.y,pC); pC=fmaf(wC2.z,h4.z,pC); pC=fmaf(wC2.w,h4.w,pC); \
          h4 = hseg[3]; \
          pA=fmaf(wA3.x,h4.x,pA); pA=fmaf(wA3.y,h4.y,pA); pA=fmaf(wA3.z,h4.z,pA); pA=fmaf(wA3.w,h4.w,pA); \
          pB=fmaf(wB3.x,h4.x,pB); pB=fmaf(wB3.y,h4.y,pB); pB=fmaf(wB3.z,h4.z,pB); pB=fmaf(wB3.w,h4.w,pB); \
          pC=fmaf(wC3.x,h4.x,pC); pC=fmaf(wC3.y,h4.y,pC); pC=fmaf(wC3.z,h4.z,pC); pC=fmaf(wC3.w,h4.w,pC); \
          h4 = hseg[4]; \
          pA=fmaf(wA4.x,h4.x,pA); pA=fmaf(wA4.y,h4.y,pA); pA=fmaf(wA4.z,h4.z,pA); pA=fmaf(wA4.w,h4.w,pA); \
          pB=fmaf(wB4.x,h4.x,pB); pB=fmaf(wB4.y,h4.y,pB); pB=fmaf(wB4.z,h4.z,pB); pB=fmaf(wB4.w,h4.w,pB); \
          pC=fmaf(wC4.x,h4.x,pC); pC=fmaf(wC4.y,h4.y,pC); pC=fmaf(wC4.z,h4.z,pC); pC=fmaf(wC4.w,h4.w,pC); \
          h4 = hseg[5]; \
          pA=fmaf(wA5.x,h4.x,pA); pA=fmaf(wA5.y,h4.y,pA); pA=fmaf(wA5.z,h4.z,pA); pA=fmaf(wA5.w,h4.w,pA); \
          pB=fmaf(wB5.x,h4.x,pB); pB=fmaf(wB5.y,h4.y,pB); pB=fmaf(wB5.z,h4.z,pB); pB=fmaf(wB5.w,h4.w,pB); \
          pC=fmaf(wC5.x,h4.x,pC); pC=fmaf(wC5.y,h4.y,pC); pC=fmaf(wC5.z,h4.z,pC); pC=fmaf(wC5.w,h4.w,pC); \
          h4 = hseg[6]; \
          pA=fmaf(wA6.x,h4.x,pA); pA=fmaf(wA6.y,h4.y,pA); pA=fmaf(wA6.z,h4.z,pA); pA=fmaf(wA6.w,h4.w,pA); \
          pB=fmaf(wB6.x,h4.x,pB); pB=fmaf(wB6.y,h4.y,pB); pB=fmaf(wB6.z,h4.z,pB); pB=fmaf(wB6.w,h4.w,pB); \
          pC=fmaf(wC6.x,h4.x,pC); pC=fmaf(wC6.y,h4.y,pC); pC=fmaf(wC6.z,h4.z,pC); pC=fmaf(wC6.w,h4.w,pC); \
          h4 = hseg[7]; \
          pA=fmaf(wA7.x,h4.x,pA); pA=fmaf(wA7.y,h4.y,pA); pA=fmaf(wA7.z,h4.z,pA); pA=fmaf(wA7.w,h4.w,pA); \
          pB=fmaf(wB7.x,h4.x,pB); pB=fmaf(wB7.y,h4.y,pB); pB=fmaf(wB7.z,h4.z,pB); pB=fmaf(wB7.w,h4.w,pB); \
          pC=fmaf(wC7.x,h4.x,pC); pC=fmaf(wC7.y,h4.y,pC); pC=fmaf(wC7.z,h4.z,pC); pC=fmaf(wC7.w,h4.w,pC); } \
        pA += __shfl_xor(pA, 16); pA += __shfl_xor(pA, 32); \
        pB += __shfl_xor(pB, 16); pB += __shfl_xor(pB, 32); \
        pC += __shfl_xor(pC, 16); pC += __shfl_xor(pC, 32); \
        if (q == 0) { \
            float r = fast_sigmoid(GR + pA + br); \
            float z = fast_sigmoid(GZ + pB + bz); \
            float n = fast_tanh(GN + r * (pC + bn)); \
            hold = (1.f - z) * n + z * hold; \
            (WR)[ji] = hold; \
            SAVE = hold; \
            const long sn = dir ? (long)s - 2 : (long)s + 2; \
            const float* gp = gbase + sn * GI_N; \
            GR = gp[0]; GZ = gp[128]; GN = gp[256]; \
        } \
        barrier_lgkm(); \
    }

    for (int step = 0; step < Sk; step += 4) {
        float h0 = 0.f, h1 = 0.f, h2 = 0.f, h3 = 0.f;
        STEP(hbufA, hbufB, dir ? (Sk - 1 - step) : step,       ar, az, an_, h0);
        STEP(hbufB, hbufA, dir ? (Sk - 2 - step) : (step + 1), brr, bzz, bnn, h1);
        STEP(hbufA, hbufB, dir ? (Sk - 3 - step) : (step + 2), ar, az, an_, h2);
        STEP(hbufB, hbufA, dir ? (Sk - 4 - step) : (step + 3), brr, bzz, bnn, h3);
        if (q == 0) {
            const size_t base = (size_t)(b * Sk) * 256 + dir * 128 + j;
            const int sA = dir ? (Sk - 1 - step) : step;
            const int d1 = dir ? -1 : 1;
            sent_rep[base + (size_t)(sA)          * 256] = h0;
            sent_rep[base + (size_t)(sA + d1)     * 256] = h1;
            sent_rep[base + (size_t)(sA + 2 * d1) * 256] = h2;
            sent_rep[base + (size_t)(sA + 3 * d1) * 256] = h3;
            srh[base + (size_t)(sA)          * 256] = f2bf(h0);
            srh[base + (size_t)(sA + d1)     * 256] = f2bf(h1);
            srh[base + (size_t)(sA + 2 * d1) * 256] = f2bf(h2);
            srh[base + (size_t)(sA + 3 * d1) * 256] = f2bf(h3);
        }
    }
    #undef STEP

    if (q == 0) hT[dir * 4096 + b * 128 + j] = hold;
}

// ---------------- prep: doc_vec + topic_mat + tidmap (fused) --------------
__device__ __forceinline__ float4 sr_load_guard(const float* sr, int b, int sidx, int j4) {
    if (sidx < 0 || sidx >= Sk) { float4 z = {0,0,0,0}; return z; }
    return reinterpret_cast<const float4*>(sr)[(size_t)(b * Sk + sidx) * 64 + j4];
}
__global__ __launch_bounds__(64) void prep_kernel(
    const int* __restrict__ tse, const float* __restrict__ sent_rep,
    const float* __restrict__ hT, float* __restrict__ dvtm,
    unsigned short* __restrict__ dvtmH, unsigned short* __restrict__ dvtmL,
    int* __restrict__ tidmap)
{
    const int b = blockIdx.x;
    const int t = blockIdx.y;
    const int j4 = threadIdx.x;
    float4 v;
    int row;
    if (t == 16) {
        int dir = b >> 4;
        int bb = 2 * (b & 15) + (j4 >> 5);
        int jj4 = j4 & 31;
        v = reinterpret_cast<const float4*>(hT)[dir * 1024 + bb * 32 + jj4];
        row = b;
        // fused tidmap for batch b
        for (int ss = j4; ss < 256; ss += 64) {
            int ti = 0;
            #pragma unroll
            for (int tt = 1; tt < 16; ++tt) ti += (ss >= tse[b * 32 + tt * 2] - 1) ? 1 : 0;
            tidmap[b * 256 + ss] = ti;
        }
    } else {
        int st = tse[b * 32 + t * 2];
        int en = tse[b * 32 + t * 2 + 1];
        float4 va, vb;
        if (j4 < 32) {
            va = sr_load_guard(sent_rep, b, en - 1, j4);
            vb = sr_load_guard(sent_rep, b, st - 2, j4);
        } else {
            va = sr_load_guard(sent_rep, b, st - 1, j4);
            vb = sr_load_guard(sent_rep, b, en, j4);
        }
        v.x = va.x - vb.x; v.y = va.y - vb.y; v.z = va.z - vb.z; v.w = va.w - vb.w;
        row = 32 + b * 16 + t;
    }
    reinterpret_cast<float4*>(dvtm)[row * 64 + j4] = v;
    ushort4 h, l;
    h.x = f2bf(v.x); h.y = f2bf(v.y); h.z = f2bf(v.z); h.w = f2bf(v.w);
    l.x = f2bf(v.x - bf2f(h.x)); l.y = f2bf(v.y - bf2f(h.y));
    l.z = f2bf(v.z - bf2f(h.z)); l.w = f2bf(v.w - bf2f(h.w));
    *reinterpret_cast<ushort4*>(dvtmH + (size_t)row * 256 + j4 * 4) = h;
    *reinterpret_cast<ushort4*>(dvtmL + (size_t)row * 256 + j4 * 4) = l;
}

// ---------------- softmax (sums partials, outputs weights) ----------------
__global__ __launch_bounds__(256) void softmax_kernel(
    const float* __restrict__ dscp, const float* __restrict__ tscp,
    float* __restrict__ dsc, float* __restrict__ tsc)
{
    const int b = blockIdx.x, sidx = threadIdx.x;
    const int lane = sidx & 63, wid = sidx >> 6;
    __shared__ float rd[4], rt[4];
    const float4* dp8 = reinterpret_cast<const float4*>(dscp + (size_t)(b * Sk + sidx) * 8);
    const float4* tp8 = reinterpret_cast<const float4*>(tscp + (size_t)(b * Sk + sidx) * 8);
    float4 d0 = dp8[0], d1 = dp8[1], t0 = tp8[0], t1 = tp8[1];
    float d = ((d0.x + d0.y) + (d0.z + d0.w)) + ((d1.x + d1.y) + (d1.z + d1.w));
    float t = ((t0.x + t0.y) + (t0.z + t0.w)) + ((t1.x + t1.y) + (t1.z + t1.w));
    float md = d, mt = t;
    #pragma unroll
    for (int off = 32; off; off >>= 1) {
        md = fmaxf(md, __shfl_xor(md, off));
        mt = fmaxf(mt, __shfl_xor(mt, off));
    }
    if (lane == 0) { rd[wid] = md; rt[wid] = mt; }
    __syncthreads();
    md = fmaxf(fmaxf(rd[0], rd[1]), fmaxf(rd[2], rd[3]));
    mt = fmaxf(fmaxf(rt[0], rt[1]), fmaxf(rt[2], rt[3]));
    float ed = __expf(d - md), et = __expf(t - mt);
    float sd = ed, stt = et;
    #pragma unroll
    for (int off = 32; off; off >>= 1) {
        sd += __shfl_xor(sd, off);
        stt += __shfl_xor(stt, off);
    }
    __syncthreads();
    if (lane == 0) { rd[wid] = sd; rt[wid] = stt; }
    __syncthreads();
    sd = rd[0] + rd[1] + rd[2] + rd[3];
    stt = rt[0] + rt[1] + rt[2] + rt[3];
    dsc[b * Sk + sidx] = ed / sd;
    tsc[b * Sk + sidx] = et / stt;
}

// ---------------- build inp (bf16 hi/lo) = [sent_rep, context] ------------
__global__ __launch_bounds__(128) void build_inp_kernel(
    const float* __restrict__ sent_rep, const float* __restrict__ dvtm,
    const float* __restrict__ dw, const float* __restrict__ tw,
    const int* __restrict__ tidmap,
    unsigned short* __restrict__ inpH, unsigned short* __restrict__ inpL)
{
    int row = blockIdx.x;
    int b = row >> 8;
    int f4c = threadIdx.x;
    float4 v;
    if (f4c < 64) {
        v = reinterpret_cast<const float4*>(sent_rep)[(size_t)row * 64 + f4c];
    } else {
        int ti = tidmap[row];
        float dwv = dw[row], twv = tw[row];
        int j4 = f4c - 64;
        float4 dv = reinterpret_cast<const float4*>(dvtm)[b * 64 + j4];
        float4 tm = reinterpret_cast<const float4*>(dvtm)[(32 + b * 16 + ti) * 64 + j4];
        v.x = dwv * dv.x + twv * tm.x;
        v.y = dwv * dv.y + twv * tm.y;
        v.z = dwv * dv.z + twv * tm.z;
        v.w = dwv * dv.w + twv * tm.w;
    }
    ushort4 h, l;
    h.x = f2bf(v.x); h.y = f2bf(v.y); h.z = f2bf(v.z); h.w = f2bf(v.w);
    l.x = f2bf(v.x - bf2f(h.x)); l.y = f2bf(v.y - bf2f(h.y));
    l.z = f2bf(v.z - bf2f(h.z)); l.w = f2bf(v.w - bf2f(h.w));
    *reinterpret_cast<ushort4*>(inpH + (size_t)row * 512 + f4c * 4) = h;
    *reinterpret_cast<ushort4*>(inpL + (size_t)row * 512 + f4c * 4) = l;
}

// ---------------- launch ----------------
extern "C" void kernel_launch(void* const* d_in, const int* in_sizes, int n_in,
                              void* d_out, int out_size, void* d_ws, size_t ws_size,
                              hipStream_t stream)
{
    const int*   wids  = (const int*)d_in[0];
    const int*   tse   = (const int*)d_in[1];
    const float* table = (const float*)d_in[2];
    const float* Wihf  = (const float*)d_in[3];
    const float* Whhf  = (const float*)d_in[4];
    const float* bihf  = (const float*)d_in[5];
    const float* bhhf  = (const float*)d_in[6];
    const float* Wihb  = (const float*)d_in[7];
    const float* Whhb  = (const float*)d_in[8];
    const float* bihb  = (const float*)d_in[9];
    const float* bhhb  = (const float*)d_in[10];
    const float* vatt  = (const float*)d_in[11];
    const float* Watt  = (const float*)d_in[12];
    const float* W1    = (const float*)d_in[13];
    const float* b1    = (const float*)d_in[14];
    const float* W2    = (const float*)d_in[15];
    const float* b2    = (const float*)d_in[16];
    float* ws = (float*)d_ws;
    float* out = (float*)d_out;

    // layout (float units)
    unsigned short* Ahi   = (unsigned short*)(ws + 0);          // 1,310,720 f
    unsigned short* Alo   = (unsigned short*)(ws + 1310720);    // 1,310,720 f
    float* gi             = ws + 2621440;                       // 6,291,456
    float* sent_rep       = ws + 8912896;                       // 2,097,152
    unsigned short* SRhi  = (unsigned short*)(ws + 11010048);   // 1,048,576 f
    float* hT             = ws + 12058624;                      // 8,192
    float* dvtm           = ws + 12066816;                      // 139,264
    float* dptp           = ws + 12206080;                      // 327,680 (640x512)
    float* dsc            = ws + 12533760;                      // 8,192
    float* tsc            = ws + 12541952;                      // 8,192
    unsigned short* BgtH  = (unsigned short*)(ws + 12550144);   // 122,880 f
    unsigned short* BgtL  = (unsigned short*)(ws + 12673024);   // 122,880 f
    float* bias_gi        = ws + 12795904;                      // 768
    unsigned short* Wswt  = (unsigned short*)(ws + 12796672);   // 65,536 f
    unsigned short* W1H   = (unsigned short*)(ws + 12862208);   // 32,768 f
    unsigned short* W1L   = (unsigned short*)(ws + 12894976);   // 32,768 f
    float* dscp           = ws + 12927744;                      // 65,536
    float* tscp           = ws + 12993280;                      // 65,536
    int*   tidmap         = (int*)(ws + 13058816);              // 8,192
    unsigned short* dvtmH = (unsigned short*)(ws + 13067008);   // 81,920 f (640x256)
    unsigned short* dvtmL = (unsigned short*)(ws + 13148928);   // 81,920 f
    unsigned short* WatTH = (unsigned short*)(ws + 13230848);   // 65,536 f
    unsigned short* WatTL = (unsigned short*)(ws + 13296384);   // 65,536 f
    // end 13,361,920 floats
    // dead-zone reuse (Ahi/Alo/gi dead after scan):
    unsigned short* inpH  = (unsigned short*)(ws + 0);          // 2,097,152 f
    unsigned short* inpL  = (unsigned short*)(ws + 2097152);    // 2,097,152 f

    if (ws_size < (size_t)13361920 * sizeof(float)) return;

    pack_kernel<<<960, 256, 0, stream>>>(Wihf, Wihb, bihf, bihb, Watt, W1,
                                         BgtH, BgtL, bias_gi, Wswt, W1H, W1L,
                                         WatTH, WatTL);
    embed_mean_kernel<<<2048, 256, 0, stream>>>(wids, table, Ahi, Alo);
    mfma_gemm_kernel<3, true, false><<<dim3(64, 6), 256, 0, stream>>>(
        Ahi, Alo, BgtH, BgtL, bias_gi, gi, NROWS, 768, KPAD);
    gru_scan_kernel<<<64, 512, 0, stream>>>(gi, Whhf, Whhb, bhhf, bhhb,
                                            sent_rep, SRhi, hT);
    prep_kernel<<<dim3(32, 17), 64, 0, stream>>>(tse, sent_rep, hT, dvtm,
                                                 dvtmH, dvtmL, tidmap);
    mfma_gemm_kernel<3, false, false><<<dim3(5, 4), 256, 0, stream>>>(
        dvtmH, dvtmL, WatTH, WatTL, nullptr, dptp, 640, 512, 256);
    mfma_swscore_kernel<<<dim3(64, 4), 256, 0, stream>>>(
        SRhi, Wswt, dptp, vatt, tidmap, dscp, tscp);
    softmax_kernel<<<32, 256, 0, stream>>>(dscp, tscp, dsc, tsc);
    build_inp_kernel<<<NROWS, 128, 0, stream>>>(sent_rep, dvtm, dsc, tsc, tidmap, inpH, inpL);
    mfma_w1_logits_kernel<<<dim3(64, 1), 256, 0, stream>>>(
        inpH, inpL, W1H, W1L, b1, W2, b2, out);
}